// Round 2
// baseline (1001.396 us; speedup 1.0000x reference)
//
#include <hip/hip_runtime.h>
#include <cmath>
#include <cstdint>

// ---------------------------------------------------------------------------
// MemoryPlus: q = x@w_q^T; sims = norm(q)@norm(keys)^T; top-32 + softmax;
// mem_out = sum_k w_k * values[idx_k]; out = (mem_out * silu(x@w_gate^T)) @ w_out^T
//
// R4->R5 (sims_coarse only; selection math unchanged):
//  (a) launch_bounds (256,4)->(256,2). The (256,4) bound capped the unified
//      VGPR+AGPR file at 128/thread; the body needs ~145 (64 AGPR acc +
//      32 prefetch + 32 frags + addr), so the compiler spilled the prefetch
//      regs to scratch every K-chunk: ~1.1 GB/dispatch of scratch stores
//      (= observed WRITE_SIZE 1.13 GB vs ~3 MB of real writes), MfmaUtil 6%.
//  (b) XCD-grouped block swizzle (flat grid 1024, nwg%8==0 bijective):
//      XCD k handles key-slices {4k..4k+3} -> per-XCD L2 working set
//      2 MB kh + 2 MB qh < 4 MB. R4 had ~0% L2 reuse (FETCH 600 MB ~= the
//      576 MB of logical reads).
// R6: identical resubmission of R5 (bench infra failed; no counters).
// ---------------------------------------------------------------------------

typedef unsigned short ushort_t;
typedef __bf16 bf16x8 __attribute__((ext_vector_type(8)));
typedef float floatx4 __attribute__((ext_vector_type(4)));

#define TAU 0.16f
#define CAP 512

__device__ __forceinline__ float wave_sum(float v) {
#pragma unroll
  for (int o = 32; o > 0; o >>= 1) v += __shfl_xor(v, o, 64);
  return v;
}

__device__ __forceinline__ unsigned long long pack_vi(float v, int idx) {
  const unsigned int b = __float_as_uint(v);
  const unsigned int fk = (b & 0x80000000u) ? ~b : (b | 0x80000000u);
  return ((unsigned long long)fk << 32) | (unsigned int)(~idx);
}
__device__ __forceinline__ float unpack_v(unsigned long long k) {
  const unsigned int fk = (unsigned int)(k >> 32);
  const unsigned int b = (fk & 0x80000000u) ? (fk & 0x7FFFFFFFu) : ~fk;
  return __uint_as_float(b);
}
__device__ __forceinline__ int unpack_i(unsigned long long k) {
  return ~(int)(unsigned int)(k & 0xFFFFFFFFu);
}

__device__ __forceinline__ ushort_t f2bf_rne(float f) {
  const unsigned int u = __float_as_uint(f);
  return (ushort_t)((u + 0x7FFFu + ((u >> 16) & 1u)) >> 16);
}

__global__ __launch_bounds__(256) void zero_kernel(int* __restrict__ p) {
  p[blockIdx.x * 256 + threadIdx.x] = 0;
}

// inverse L2 norm of each 256-float row (matches F.normalize: 1/max(||v||,1e-12))
__global__ __launch_bounds__(256) void rownorm_inv_kernel(const float* __restrict__ rows,
                                                          float* __restrict__ inv) {
  const int r = blockIdx.x * 4 + (threadIdx.x >> 6);
  const int lane = threadIdx.x & 63;
  const float4 v = ((const float4*)(rows + (long)r * 256))[lane];
  float s = v.x * v.x + v.y * v.y + v.z * v.z + v.w * v.w;
  s = wave_sum(s);
  if (lane == 0) inv[r] = 1.0f / fmaxf(sqrtf(s), 1e-12f);
}

// out_bf16[r][c] = bf16(rows[r][c] * inv[r]), rows of 256. One float4 per thread.
__global__ __launch_bounds__(256) void cast_norm_kernel(const float* __restrict__ rows,
                                                        const float* __restrict__ inv,
                                                        ushort_t* __restrict__ out) {
  const long idx = (long)blockIdx.x * 256 + threadIdx.x;  // float4 index
  const int r = (int)(idx >> 6);
  const float s = inv[r];
  const float4 v = ((const float4*)rows)[idx];
  ushort4 o;
  o.x = f2bf_rne(v.x * s); o.y = f2bf_rne(v.y * s);
  o.z = f2bf_rne(v.z * s); o.w = f2bf_rne(v.w * s);
  ((ushort4*)out)[idx] = o;
}

// plain fp32 -> bf16 cast, one float4 per thread
__global__ __launch_bounds__(256) void cast_bf16_kernel(const float* __restrict__ in,
                                                        ushort_t* __restrict__ out) {
  const long idx = (long)blockIdx.x * 256 + threadIdx.x;
  const float4 v = ((const float4*)in)[idx];
  ushort4 o;
  o.x = f2bf_rne(v.x); o.y = f2bf_rne(v.y);
  o.z = f2bf_rne(v.z); o.w = f2bf_rne(v.w);
  ((ushort4*)out)[idx] = o;
}

// fp32 q GEMM: C[4096,256] = A[4096,1024] @ B[256,1024]^T. 64x64 tile,
// 4x4/thread, BK=32. grid (4,64)=256 blocks (q feeds exact rescore: fp32).
__global__ __launch_bounds__(256) void qgemm_kernel(const float* __restrict__ A,
                                                    const float* __restrict__ B,
                                                    float* __restrict__ C) {
  __shared__ float As[32][64];
  __shared__ float Bs[32][64];
  const int t = threadIdx.x;
  const int tx = t & 15, ty = t >> 4;
  const int m0 = blockIdx.y * 64, n0 = blockIdx.x * 64;
  const int lr = t >> 2;          // staged row 0..63 (4 threads/row)
  const int lk = (t & 3) * 8;     // k offset 0,8,16,24
  const float* Ap = A + (long)(m0 + lr) * 1024 + lk;
  const float* Bp = B + (long)(n0 + lr) * 1024 + lk;
  float acc[4][4] = {};
  for (int kc = 0; kc < 1024; kc += 32) {
    const float4 a0 = *(const float4*)(Ap + kc);
    const float4 a1 = *(const float4*)(Ap + kc + 4);
    const float4 b0 = *(const float4*)(Bp + kc);
    const float4 b1 = *(const float4*)(Bp + kc + 4);
    __syncthreads();
    As[lk + 0][lr] = a0.x; As[lk + 1][lr] = a0.y; As[lk + 2][lr] = a0.z; As[lk + 3][lr] = a0.w;
    As[lk + 4][lr] = a1.x; As[lk + 5][lr] = a1.y; As[lk + 6][lr] = a1.z; As[lk + 7][lr] = a1.w;
    Bs[lk + 0][lr] = b0.x; Bs[lk + 1][lr] = b0.y; Bs[lk + 2][lr] = b0.z; Bs[lk + 3][lr] = b0.w;
    Bs[lk + 4][lr] = b1.x; Bs[lk + 5][lr] = b1.y; Bs[lk + 6][lr] = b1.z; Bs[lk + 7][lr] = b1.w;
    __syncthreads();
#pragma unroll
    for (int kk = 0; kk < 32; kk++) {
      const float4 a = *(const float4*)&As[kk][ty * 4];
      const float4 b = *(const float4*)&Bs[kk][tx * 4];
      const float av[4] = {a.x, a.y, a.z, a.w};
      const float bv[4] = {b.x, b.y, b.z, b.w};
#pragma unroll
      for (int i = 0; i < 4; i++)
#pragma unroll
        for (int j = 0; j < 4; j++) acc[i][j] = fmaf(av[i], bv[j], acc[i][j]);
    }
  }
#pragma unroll
  for (int i = 0; i < 4; i++) {
    float* Cr = C + (long)(m0 + ty * 4 + i) * 256 + n0 + tx * 4;
    *(float4*)Cr = make_float4(acc[i][0], acc[i][1], acc[i][2], acc[i][3]);
  }
}

// bf16 MFMA GEMM: C[M,N] fp32 = A[M,K]bf16 @ B[N,K]bf16^T. 128x128 tile,
// 4 waves each 64x64 (4x4 of 16x16x32), BK=64, register-prefetch pipeline.
template <int EP>  // 0 = none, 1 = silu
__global__ __launch_bounds__(256, 2) void hgemm_bt_kernel(const ushort_t* __restrict__ A,
                                                          const ushort_t* __restrict__ B,
                                                          float* __restrict__ C,
                                                          int M, int N, int K) {
  __shared__ ushort_t As[128][72];
  __shared__ ushort_t Bs[128][72];
  const int t = threadIdx.x;
  const int m0 = blockIdx.y * 128, n0 = blockIdx.x * 128;
  const int lane = t & 63, wv = t >> 6;
  const int wr = wv >> 1, wc = wv & 1;
  const int q4 = lane >> 4, lx = lane & 15;
  const int r0 = t >> 3, sg = t & 7;
  const floatx4 vzero = {0.f, 0.f, 0.f, 0.f};
  floatx4 acc[4][4];
#pragma unroll
  for (int i = 0; i < 4; i++)
#pragma unroll
    for (int j = 0; j < 4; j++) acc[i][j] = vzero;

  uint4 pa[4], pb[4];
#pragma unroll
  for (int it = 0; it < 4; it++) {
    const int row = it * 32 + r0;
    pa[it] = *(const uint4*)(A + (long)(m0 + row) * K + sg * 8);
    pb[it] = *(const uint4*)(B + (long)(n0 + row) * K + sg * 8);
  }
  const int NC = K >> 6;
  for (int c = 0; c < NC; ++c) {
    __syncthreads();
#pragma unroll
    for (int it = 0; it < 4; it++) {
      const int row = it * 32 + r0;
      *(uint4*)&As[row][sg * 8] = pa[it];
      *(uint4*)&Bs[row][sg * 8] = pb[it];
    }
    if (c + 1 < NC) {
      const int c0 = (c + 1) * 64;
#pragma unroll
      for (int it = 0; it < 4; it++) {
        const int row = it * 32 + r0;
        pa[it] = *(const uint4*)(A + (long)(m0 + row) * K + c0 + sg * 8);
        pb[it] = *(const uint4*)(B + (long)(n0 + row) * K + c0 + sg * 8);
      }
    }
    __syncthreads();
#pragma unroll
    for (int ks = 0; ks < 2; ++ks) {
      bf16x8 af[4], bfr[4];
#pragma unroll
      for (int i = 0; i < 4; i++)
        af[i] = *(const bf16x8*)&As[wr * 64 + i * 16 + lx][ks * 32 + q4 * 8];
#pragma unroll
      for (int j = 0; j < 4; j++)
        bfr[j] = *(const bf16x8*)&Bs[wc * 64 + j * 16 + lx][ks * 32 + q4 * 8];
#pragma unroll
      for (int i = 0; i < 4; i++)
#pragma unroll
        for (int j = 0; j < 4; j++)
          acc[i][j] = __builtin_amdgcn_mfma_f32_16x16x32_bf16(af[i], bfr[j], acc[i][j], 0, 0, 0);
    }
  }
#pragma unroll
  for (int i = 0; i < 4; i++)
#pragma unroll
    for (int j = 0; j < 4; j++) {
      const int col = n0 + wc * 64 + j * 16 + lx;
#pragma unroll
      for (int r = 0; r < 4; r++) {
        const int row = m0 + wr * 64 + i * 16 + q4 * 4 + r;
        float v = acc[i][j][r];
        if (EP == 1) v = v / (1.0f + expf(-v));  // silu
        C[(long)row * N + col] = v;
      }
    }
}

// ---------------------------------------------------------------------------
// Coarse sims: bf16 MFMA GEMM, block = 128 q-rows x 1024 keys (8 tiles of
// 128), K=256 in 4 chunks of 64, register-prefetch. After each tile, each
// thread appends acc values > TAU as packed u32 (fp32 top 17 bits | idx) to a
// per-row global candidate list. No barriers/LDS for selection.
// R5: (256,2) so the ~145 unified regs fit without scratch spill; flat grid
// 1024 with XCD-grouped swizzle (xcd = bid&7 round-robin dispatch): XCD k
// owns key-slices {4k..4k+3} so kh re-reads hit the XCD's own L2.
// ---------------------------------------------------------------------------
__global__ __launch_bounds__(256, 2) void sims_coarse_kernel(const ushort_t* __restrict__ qh,
                                                             const ushort_t* __restrict__ kh,
                                                             int* __restrict__ cnt,
                                                             unsigned int* __restrict__ cand) {
  __shared__ ushort_t As[128][72];
  __shared__ ushort_t Bs[128][72];
  const int t = threadIdx.x;
  // XCD-grouped bijective swizzle (1024 blocks, 8 XCDs, nwg%8==0):
  const int bid = blockIdx.x;
  const int xcd = bid & 7;
  const int jj = bid >> 3;              // 0..127 within XCD
  const int cs = xcd * 4 + (jj >> 5);   // key-slice 0..31 (4 per XCD)
  const int rb = jj & 31;               // q-row-block 0..31
  const int m0 = rb * 128;
  const int lane = t & 63, wv = t >> 6;
  const int wr = wv >> 1, wc = wv & 1;
  const int q4 = lane >> 4, lx = lane & 15;
  const int r0 = t >> 3, sg = t & 7;

  uint4 pa[4], pb[4];
  {
    const int n0 = cs * 1024;
#pragma unroll
    for (int it = 0; it < 4; it++) {
      const int row = it * 32 + r0;
      pa[it] = *(const uint4*)(qh + (long)(m0 + row) * 256 + sg * 8);
      pb[it] = *(const uint4*)(kh + (long)(n0 + row) * 256 + sg * 8);
    }
  }

  for (int tile = 0; tile < 8; ++tile) {
    const int n0 = cs * 1024 + tile * 128;
    const floatx4 vzero = {0.f, 0.f, 0.f, 0.f};
    floatx4 acc[4][4];
#pragma unroll
    for (int i = 0; i < 4; i++)
#pragma unroll
      for (int j = 0; j < 4; j++) acc[i][j] = vzero;

    for (int chunk = 0; chunk < 4; ++chunk) {
      __syncthreads();
#pragma unroll
      for (int it = 0; it < 4; it++) {
        const int row = it * 32 + r0;
        *(uint4*)&As[row][sg * 8] = pa[it];
        *(uint4*)&Bs[row][sg * 8] = pb[it];
      }
      int nc = chunk + 1, nt = tile;
      if (nc == 4) { nc = 0; nt = tile + 1; }
      if (nt < 8) {
        const int nn0 = cs * 1024 + nt * 128;
        const int c0 = nc * 64;
#pragma unroll
        for (int it = 0; it < 4; it++) {
          const int row = it * 32 + r0;
          pa[it] = *(const uint4*)(qh + (long)(m0 + row) * 256 + c0 + sg * 8);
          pb[it] = *(const uint4*)(kh + (long)(nn0 + row) * 256 + c0 + sg * 8);
        }
      }
      __syncthreads();
#pragma unroll
      for (int ks = 0; ks < 2; ++ks) {
        bf16x8 af[4], bfr[4];
#pragma unroll
        for (int i = 0; i < 4; i++)
          af[i] = *(const bf16x8*)&As[wr * 64 + i * 16 + lx][ks * 32 + q4 * 8];
#pragma unroll
        for (int j = 0; j < 4; j++)
          bfr[j] = *(const bf16x8*)&Bs[wc * 64 + j * 16 + lx][ks * 32 + q4 * 8];
#pragma unroll
        for (int i = 0; i < 4; i++)
#pragma unroll
          for (int j = 0; j < 4; j++)
            acc[i][j] = __builtin_amdgcn_mfma_f32_16x16x32_bf16(af[i], bfr[j], acc[i][j], 0, 0, 0);
      }
    }

    // threshold scan + global append (rare: ~0.5% of values pass)
#pragma unroll
    for (int i = 0; i < 4; i++)
#pragma unroll
      for (int j = 0; j < 4; j++)
#pragma unroll
        for (int r = 0; r < 4; r++) {
          const float v = acc[i][j][r];
          if (v > TAU) {
            const int row = m0 + wr * 64 + i * 16 + q4 * 4 + r;
            const int idx = n0 + wc * 64 + j * 16 + lx;
            const int slot = atomicAdd(&cnt[row], 1);
            if (slot < CAP)
              cand[(long)row * CAP + slot] =
                  (__float_as_uint(v) & 0xFFFF8000u) | (unsigned int)idx;
          }
        }
  }
}

// ---------------------------------------------------------------------------
// Refine: one wave per row. Coarse top-48 of the candidate list (monotone u32
// keys), exact fp32 rescore vs original keys, exact top-32 (jax tie-break:
// value desc then idx asc), softmax.
// ---------------------------------------------------------------------------
__global__ __launch_bounds__(256) void refine_kernel(const float* __restrict__ q,
                                                     const float* __restrict__ qinv,
                                                     const float* __restrict__ keys,
                                                     const float* __restrict__ kinv,
                                                     const int* __restrict__ cnt,
                                                     const unsigned int* __restrict__ cand,
                                                     float* __restrict__ w_top,
                                                     int* __restrict__ i_top) {
  const int row = blockIdx.x * 4 + (threadIdx.x >> 6);
  const int lane = threadIdx.x & 63;
  // q-hat fragment (4 k-dims per lane), same elementwise values as numpy's q_norm
  const float qs = qinv[row];
  float4 qh = ((const float4*)(q + (long)row * 256))[lane];
  qh.x *= qs; qh.y *= qs; qh.z *= qs; qh.w *= qs;
  int ncand = cnt[row];
  if (ncand > CAP) ncand = CAP;
  unsigned int loc[8];
#pragma unroll
  for (int s = 0; s < 8; s++) {
    const int c = s * 64 + lane;
    loc[s] = (c < ncand) ? cand[(long)row * CAP + c] : 0u;
  }
  // coarse top-48 by u32 key (monotone in bf16 sim; ties resolved by rescore)
  unsigned int mykey = 0;
  for (int it = 0; it < 48; ++it) {
    unsigned int best = loc[0];
#pragma unroll
    for (int s = 1; s < 8; s++) best = (loc[s] > best) ? loc[s] : best;
#pragma unroll
    for (int o = 32; o > 0; o >>= 1) {
      const unsigned int oth = __shfl_xor(best, o, 64);
      if (oth > best) best = oth;
    }
    if (best == 0u) break;  // wave-uniform: list exhausted
#pragma unroll
    for (int s = 0; s < 8; s++)
      if (loc[s] == best) loc[s] = 0;  // keys unique per row
    if (lane == it) mykey = best;
  }
  const int myidx = (int)(mykey & 0x7FFFu);
  // exact fp32 rescore of the (up to) 48
  float myexact = 0.0f;
  for (int c = 0; c < 48; ++c) {
    const unsigned int ky = __shfl(mykey, c, 64);
    if (ky == 0u) continue;  // wave-uniform branch
    const int idx = (int)(ky & 0x7FFFu);
    const float4 kv = ((const float4*)(keys + (long)idx * 256))[lane];
    float d = qh.x * kv.x + qh.y * kv.y + qh.z * kv.z + qh.w * kv.w;
    d = wave_sum(d);
    const float sim = d * kinv[idx];
    if (lane == c) myexact = sim;
  }
  // exact top-32 with jax tie-break (value desc, idx asc)
  unsigned long long ekey = (lane < 48 && mykey != 0u) ? pack_vi(myexact, myidx) : 0ULL;
  unsigned long long sel = 0;
  float maxv = 0.0f;
  for (int it = 0; it < 32; ++it) {
    unsigned long long best = ekey;
#pragma unroll
    for (int o = 32; o > 0; o >>= 1) {
      const unsigned long long oth = __shfl_xor(best, o, 64);
      if (oth > best) best = oth;
    }
    if (ekey == best) ekey = 0;
    if (lane == it) sel = best;
    if (it == 0) maxv = unpack_v(best);
  }
  float e = 0.0f;
  int oidx = 0;
  if (lane < 32) {
    e = expf(unpack_v(sel) - maxv);
    oidx = unpack_i(sel);
  }
  const float ssum = wave_sum(e);
  if (lane < 32) {
    w_top[(long)row * 32 + lane] = e / ssum;
    i_top[(long)row * 32 + lane] = oidx;
  }
}

// mem_out = sum_k w_k * values[idx_k]; h = bf16(mem_out * gate). One block/row.
__global__ __launch_bounds__(256) void gather_gate_kernel(const float* __restrict__ values,
                                                          const float* __restrict__ w_top,
                                                          const int* __restrict__ i_top,
                                                          const float* __restrict__ gate,
                                                          ushort_t* __restrict__ h) {
  __shared__ float w[32];
  __shared__ int ix[32];
  const int row = blockIdx.x;
  const int t = threadIdx.x;
  if (t < 32) {
    w[t] = w_top[(long)row * 32 + t];
    ix[t] = i_top[(long)row * 32 + t];
  }
  __syncthreads();
  float4 acc = make_float4(0.f, 0.f, 0.f, 0.f);
#pragma unroll 4
  for (int k = 0; k < 32; k++) {
    const float4 v = *(const float4*)(values + (long)ix[k] * 1024 + t * 4);
    const float wk = w[k];
    acc.x = fmaf(wk, v.x, acc.x);
    acc.y = fmaf(wk, v.y, acc.y);
    acc.z = fmaf(wk, v.z, acc.z);
    acc.w = fmaf(wk, v.w, acc.w);
  }
  const float4 g = *(const float4*)(gate + (long)row * 1024 + t * 4);
  ushort4 o;
  o.x = f2bf_rne(acc.x * g.x); o.y = f2bf_rne(acc.y * g.y);
  o.z = f2bf_rne(acc.z * g.z); o.w = f2bf_rne(acc.w * g.w);
  ((ushort4*)(h + (long)row * 1024))[t] = o;
}

extern "C" void kernel_launch(void* const* d_in, const int* in_sizes, int n_in,
                              void* d_out, int out_size, void* d_ws, size_t ws_size,
                              hipStream_t stream) {
  const float* x      = (const float*)d_in[0];  // [4,1024,1024]
  const float* keys   = (const float*)d_in[1];  // [32768,256]
  const float* values = (const float*)d_in[2];  // [32768,1024]
  const float* w_q    = (const float*)d_in[3];  // [256,1024]
  const float* w_gate = (const float*)d_in[4];  // [1024,1024]
  const float* w_out  = (const float*)d_in[5];  // [1024,1024]
  float* out = (float*)d_out;                   // [4,1024,1024]

  // workspace layout (4-byte units), ~51.5 MB total
  float* q        = (float*)d_ws;                   // 1,048,576
  float* qinv     = q + 1048576;                    // 4096
  float* kinv     = qinv + 4096;                    // 32768
  int*   cnt      = (int*)(kinv + 32768);           // 4096
  float* w_top    = (float*)(cnt + 4096);           // 131072
  int*   i_top    = (int*)(w_top + 131072);         // 131072
  ushort_t* qh    = (ushort_t*)(i_top + 131072);    // 524,288 f
  float* khf      = (float*)(qh + 1048576);         // 4,194,304 f region
  ushort_t* kh    = (ushort_t*)khf;                 //   [cast -> sims]
  ushort_t* hbf   = (ushort_t*)khf;                 //   alias: h bf16 [gather -> out GEMM]
  ushort_t* wo    = (ushort_t*)(khf + 2097152);     //   alias: w_out bf16 [after sims]
  float* gate     = khf + 4194304;                  // 4,194,304 f
  float* xbfr     = gate + 4194304;                 // 2,097,152 f region
  ushort_t* xb    = (ushort_t*)xbfr;                //   x bf16 [cast -> gate GEMM]
  unsigned int* cand = (unsigned int*)xbfr;         //   alias: candidates [sims -> refine]
  ushort_t* wg    = (ushort_t*)(xbfr + 2097152);    // 524,288 f

  zero_kernel<<<dim3(16), 256, 0, stream>>>(cnt);
  qgemm_kernel<<<dim3(4, 64), 256, 0, stream>>>(x, w_q, q);
  rownorm_inv_kernel<<<dim3(32768 / 4), 256, 0, stream>>>(keys, kinv);
  rownorm_inv_kernel<<<dim3(4096 / 4), 256, 0, stream>>>(q, qinv);
  cast_norm_kernel<<<dim3(4096 * 64 / 256), 256, 0, stream>>>(q, qinv, qh);
  cast_norm_kernel<<<dim3(32768 * 64 / 256), 256, 0, stream>>>(keys, kinv, kh);
  cast_bf16_kernel<<<dim3(4096), 256, 0, stream>>>(x, xb);
  cast_bf16_kernel<<<dim3(1024), 256, 0, stream>>>(w_gate, wg);
  // gate GEMM must precede sims (cand aliases xb)
  hgemm_bt_kernel<1><<<dim3(8, 32), 256, 0, stream>>>(xb, wg, gate, 4096, 1024, 1024);
  sims_coarse_kernel<<<dim3(1024), 256, 0, stream>>>(qh, kh, cnt, cand);
  // w_out cast must follow sims (wo aliases kh region)
  cast_bf16_kernel<<<dim3(1024), 256, 0, stream>>>(w_out, wo);
  refine_kernel<<<dim3(4096 / 4), 256, 0, stream>>>(q, qinv, keys, kinv, cnt, cand, w_top, i_top);
  gather_gate_kernel<<<dim3(4096), 256, 0, stream>>>(values, w_top, i_top, gate, hbf);
  hgemm_bt_kernel<0><<<dim3(8, 32), 256, 0, stream>>>(hbf, wo, out, 4096, 1024, 1024);
}

// Round 4
// 888.181 us; speedup vs baseline: 1.1275x; 1.1275x over previous
//
#include <hip/hip_runtime.h>
#include <cmath>
#include <cstdint>

// ---------------------------------------------------------------------------
// MemoryPlus: q = x@w_q^T; sims = norm(q)@norm(keys)^T; top-32 + softmax;
// mem_out = sum_k w_k * values[idx_k]; out = (mem_out * silu(x@w_gate^T)) @ w_out^T
//
// R7 (sims_coarse scan only; GEMM + selection math unchanged):
//  R4/R5 showed dur invariant (445->448 us) under halved traffic AND halved
//  occupancy -> bottleneck is the unchanged per-value global atomic append:
//  ~700K divergent atomicAdd to a 16KB cnt[] contended by all 8 XCDs
//  (cross-XCD RMW ping-pong ~1-5K cyc), drained at every tile barrier.
//  Fix: per-row LDS candidate lists (128x32, overflow->global fallback),
//  ballot-batched LDS atomics in the scan, ONE global atomic per row per
//  block at kernel end (~131K total vs 700K, outside the MFMA pipeline).
// R8: identical resubmission of R7 (bench infra failed; no counters).
// ---------------------------------------------------------------------------

typedef unsigned short ushort_t;
typedef __bf16 bf16x8 __attribute__((ext_vector_type(8)));
typedef float floatx4 __attribute__((ext_vector_type(4)));

#define TAU 0.16f
#define CAP 512
#define LCAP 32

__device__ __forceinline__ float wave_sum(float v) {
#pragma unroll
  for (int o = 32; o > 0; o >>= 1) v += __shfl_xor(v, o, 64);
  return v;
}

__device__ __forceinline__ unsigned long long pack_vi(float v, int idx) {
  const unsigned int b = __float_as_uint(v);
  const unsigned int fk = (b & 0x80000000u) ? ~b : (b | 0x80000000u);
  return ((unsigned long long)fk << 32) | (unsigned int)(~idx);
}
__device__ __forceinline__ float unpack_v(unsigned long long k) {
  const unsigned int fk = (unsigned int)(k >> 32);
  const unsigned int b = (fk & 0x80000000u) ? (fk & 0x7FFFFFFFu) : ~fk;
  return __uint_as_float(b);
}
__device__ __forceinline__ int unpack_i(unsigned long long k) {
  return ~(int)(unsigned int)(k & 0xFFFFFFFFu);
}

__device__ __forceinline__ ushort_t f2bf_rne(float f) {
  const unsigned int u = __float_as_uint(f);
  return (ushort_t)((u + 0x7FFFu + ((u >> 16) & 1u)) >> 16);
}

__global__ __launch_bounds__(256) void zero_kernel(int* __restrict__ p) {
  p[blockIdx.x * 256 + threadIdx.x] = 0;
}

// inverse L2 norm of each 256-float row (matches F.normalize: 1/max(||v||,1e-12))
__global__ __launch_bounds__(256) void rownorm_inv_kernel(const float* __restrict__ rows,
                                                          float* __restrict__ inv) {
  const int r = blockIdx.x * 4 + (threadIdx.x >> 6);
  const int lane = threadIdx.x & 63;
  const float4 v = ((const float4*)(rows + (long)r * 256))[lane];
  float s = v.x * v.x + v.y * v.y + v.z * v.z + v.w * v.w;
  s = wave_sum(s);
  if (lane == 0) inv[r] = 1.0f / fmaxf(sqrtf(s), 1e-12f);
}

// out_bf16[r][c] = bf16(rows[r][c] * inv[r]), rows of 256. One float4 per thread.
__global__ __launch_bounds__(256) void cast_norm_kernel(const float* __restrict__ rows,
                                                        const float* __restrict__ inv,
                                                        ushort_t* __restrict__ out) {
  const long idx = (long)blockIdx.x * 256 + threadIdx.x;  // float4 index
  const int r = (int)(idx >> 6);
  const float s = inv[r];
  const float4 v = ((const float4*)rows)[idx];
  ushort4 o;
  o.x = f2bf_rne(v.x * s); o.y = f2bf_rne(v.y * s);
  o.z = f2bf_rne(v.z * s); o.w = f2bf_rne(v.w * s);
  ((ushort4*)out)[idx] = o;
}

// plain fp32 -> bf16 cast, one float4 per thread
__global__ __launch_bounds__(256) void cast_bf16_kernel(const float* __restrict__ in,
                                                        ushort_t* __restrict__ out) {
  const long idx = (long)blockIdx.x * 256 + threadIdx.x;
  const float4 v = ((const float4*)in)[idx];
  ushort4 o;
  o.x = f2bf_rne(v.x); o.y = f2bf_rne(v.y);
  o.z = f2bf_rne(v.z); o.w = f2bf_rne(v.w);
  ((ushort4*)out)[idx] = o;
}

// fp32 q GEMM: C[4096,256] = A[4096,1024] @ B[256,1024]^T. 64x64 tile,
// 4x4/thread, BK=32. grid (4,64)=256 blocks (q feeds exact rescore: fp32).
__global__ __launch_bounds__(256) void qgemm_kernel(const float* __restrict__ A,
                                                    const float* __restrict__ B,
                                                    float* __restrict__ C) {
  __shared__ float As[32][64];
  __shared__ float Bs[32][64];
  const int t = threadIdx.x;
  const int tx = t & 15, ty = t >> 4;
  const int m0 = blockIdx.y * 64, n0 = blockIdx.x * 64;
  const int lr = t >> 2;          // staged row 0..63 (4 threads/row)
  const int lk = (t & 3) * 8;     // k offset 0,8,16,24
  const float* Ap = A + (long)(m0 + lr) * 1024 + lk;
  const float* Bp = B + (long)(n0 + lr) * 1024 + lk;
  float acc[4][4] = {};
  for (int kc = 0; kc < 1024; kc += 32) {
    const float4 a0 = *(const float4*)(Ap + kc);
    const float4 a1 = *(const float4*)(Ap + kc + 4);
    const float4 b0 = *(const float4*)(Bp + kc);
    const float4 b1 = *(const float4*)(Bp + kc + 4);
    __syncthreads();
    As[lk + 0][lr] = a0.x; As[lk + 1][lr] = a0.y; As[lk + 2][lr] = a0.z; As[lk + 3][lr] = a0.w;
    As[lk + 4][lr] = a1.x; As[lk + 5][lr] = a1.y; As[lk + 6][lr] = a1.z; As[lk + 7][lr] = a1.w;
    Bs[lk + 0][lr] = b0.x; Bs[lk + 1][lr] = b0.y; Bs[lk + 2][lr] = b0.z; Bs[lk + 3][lr] = b0.w;
    Bs[lk + 4][lr] = b1.x; Bs[lk + 5][lr] = b1.y; Bs[lk + 6][lr] = b1.z; Bs[lk + 7][lr] = b1.w;
    __syncthreads();
#pragma unroll
    for (int kk = 0; kk < 32; kk++) {
      const float4 a = *(const float4*)&As[kk][ty * 4];
      const float4 b = *(const float4*)&Bs[kk][tx * 4];
      const float av[4] = {a.x, a.y, a.z, a.w};
      const float bv[4] = {b.x, b.y, b.z, b.w};
#pragma unroll
      for (int i = 0; i < 4; i++)
#pragma unroll
        for (int j = 0; j < 4; j++) acc[i][j] = fmaf(av[i], bv[j], acc[i][j]);
    }
  }
#pragma unroll
  for (int i = 0; i < 4; i++) {
    float* Cr = C + (long)(m0 + ty * 4 + i) * 256 + n0 + tx * 4;
    *(float4*)Cr = make_float4(acc[i][0], acc[i][1], acc[i][2], acc[i][3]);
  }
}

// bf16 MFMA GEMM: C[M,N] fp32 = A[M,K]bf16 @ B[N,K]bf16^T. 128x128 tile,
// 4 waves each 64x64 (4x4 of 16x16x32), BK=64, register-prefetch pipeline.
template <int EP>  // 0 = none, 1 = silu
__global__ __launch_bounds__(256, 2) void hgemm_bt_kernel(const ushort_t* __restrict__ A,
                                                          const ushort_t* __restrict__ B,
                                                          float* __restrict__ C,
                                                          int M, int N, int K) {
  __shared__ ushort_t As[128][72];
  __shared__ ushort_t Bs[128][72];
  const int t = threadIdx.x;
  const int m0 = blockIdx.y * 128, n0 = blockIdx.x * 128;
  const int lane = t & 63, wv = t >> 6;
  const int wr = wv >> 1, wc = wv & 1;
  const int q4 = lane >> 4, lx = lane & 15;
  const int r0 = t >> 3, sg = t & 7;
  const floatx4 vzero = {0.f, 0.f, 0.f, 0.f};
  floatx4 acc[4][4];
#pragma unroll
  for (int i = 0; i < 4; i++)
#pragma unroll
    for (int j = 0; j < 4; j++) acc[i][j] = vzero;

  uint4 pa[4], pb[4];
#pragma unroll
  for (int it = 0; it < 4; it++) {
    const int row = it * 32 + r0;
    pa[it] = *(const uint4*)(A + (long)(m0 + row) * K + sg * 8);
    pb[it] = *(const uint4*)(B + (long)(n0 + row) * K + sg * 8);
  }
  const int NC = K >> 6;
  for (int c = 0; c < NC; ++c) {
    __syncthreads();
#pragma unroll
    for (int it = 0; it < 4; it++) {
      const int row = it * 32 + r0;
      *(uint4*)&As[row][sg * 8] = pa[it];
      *(uint4*)&Bs[row][sg * 8] = pb[it];
    }
    if (c + 1 < NC) {
      const int c0 = (c + 1) * 64;
#pragma unroll
      for (int it = 0; it < 4; it++) {
        const int row = it * 32 + r0;
        pa[it] = *(const uint4*)(A + (long)(m0 + row) * K + c0 + sg * 8);
        pb[it] = *(const uint4*)(B + (long)(n0 + row) * K + c0 + sg * 8);
      }
    }
    __syncthreads();
#pragma unroll
    for (int ks = 0; ks < 2; ++ks) {
      bf16x8 af[4], bfr[4];
#pragma unroll
      for (int i = 0; i < 4; i++)
        af[i] = *(const bf16x8*)&As[wr * 64 + i * 16 + lx][ks * 32 + q4 * 8];
#pragma unroll
      for (int j = 0; j < 4; j++)
        bfr[j] = *(const bf16x8*)&Bs[wc * 64 + j * 16 + lx][ks * 32 + q4 * 8];
#pragma unroll
      for (int i = 0; i < 4; i++)
#pragma unroll
        for (int j = 0; j < 4; j++)
          acc[i][j] = __builtin_amdgcn_mfma_f32_16x16x32_bf16(af[i], bfr[j], acc[i][j], 0, 0, 0);
    }
  }
#pragma unroll
  for (int i = 0; i < 4; i++)
#pragma unroll
    for (int j = 0; j < 4; j++) {
      const int col = n0 + wc * 64 + j * 16 + lx;
#pragma unroll
      for (int r = 0; r < 4; r++) {
        const int row = m0 + wr * 64 + i * 16 + q4 * 4 + r;
        float v = acc[i][j][r];
        if (EP == 1) v = v / (1.0f + expf(-v));  // silu
        C[(long)row * N + col] = v;
      }
    }
}

// ---------------------------------------------------------------------------
// Coarse sims: bf16 MFMA GEMM, block = 128 q-rows x 1024 keys (8 tiles of
// 128), K=256 in 4 chunks of 64, register-prefetch. Candidates (> TAU) are
// appended to per-row LDS lists via ballot-batched LDS atomics; ONE global
// atomic per row per block flushes them at kernel end. Overflow beyond LCAP
// (P ~ 1e-16 at mean 5.3) falls back to the direct global append.
// ---------------------------------------------------------------------------
__global__ __launch_bounds__(256, 2) void sims_coarse_kernel(const ushort_t* __restrict__ qh,
                                                             const ushort_t* __restrict__ kh,
                                                             int* __restrict__ cnt,
                                                             unsigned int* __restrict__ cand) {
  __shared__ ushort_t As[128][72];
  __shared__ ushort_t Bs[128][72];
  __shared__ unsigned int lds_list[128][LCAP];
  __shared__ int lcnt[128];
  const int t = threadIdx.x;
  // XCD-grouped bijective swizzle (1024 blocks, 8 XCDs, nwg%8==0):
  const int bid = blockIdx.x;
  const int xcd = bid & 7;
  const int jj = bid >> 3;              // 0..127 within XCD
  const int cs = xcd * 4 + (jj >> 5);   // key-slice 0..31 (4 per XCD)
  const int rb = jj & 31;               // q-row-block 0..31
  const int m0 = rb * 128;
  const int lane = t & 63, wv = t >> 6;
  const int wr = wv >> 1, wc = wv & 1;
  const int q4 = lane >> 4, lx = lane & 15;
  const int r0 = t >> 3, sg = t & 7;

  if (t < 128) lcnt[t] = 0;  // ordered before first scan by chunk-loop barriers

  uint4 pa[4], pb[4];
  {
    const int n0 = cs * 1024;
#pragma unroll
    for (int it = 0; it < 4; it++) {
      const int row = it * 32 + r0;
      pa[it] = *(const uint4*)(qh + (long)(m0 + row) * 256 + sg * 8);
      pb[it] = *(const uint4*)(kh + (long)(n0 + row) * 256 + sg * 8);
    }
  }

  for (int tile = 0; tile < 8; ++tile) {
    const int n0 = cs * 1024 + tile * 128;
    const floatx4 vzero = {0.f, 0.f, 0.f, 0.f};
    floatx4 acc[4][4];
#pragma unroll
    for (int i = 0; i < 4; i++)
#pragma unroll
      for (int j = 0; j < 4; j++) acc[i][j] = vzero;

    for (int chunk = 0; chunk < 4; ++chunk) {
      __syncthreads();
#pragma unroll
      for (int it = 0; it < 4; it++) {
        const int row = it * 32 + r0;
        *(uint4*)&As[row][sg * 8] = pa[it];
        *(uint4*)&Bs[row][sg * 8] = pb[it];
      }
      int nc = chunk + 1, nt = tile;
      if (nc == 4) { nc = 0; nt = tile + 1; }
      if (nt < 8) {
        const int nn0 = cs * 1024 + nt * 128;
        const int c0 = nc * 64;
#pragma unroll
        for (int it = 0; it < 4; it++) {
          const int row = it * 32 + r0;
          pa[it] = *(const uint4*)(qh + (long)(m0 + row) * 256 + c0 + sg * 8);
          pb[it] = *(const uint4*)(kh + (long)(nn0 + row) * 256 + c0 + sg * 8);
        }
      }
      __syncthreads();
#pragma unroll
      for (int ks = 0; ks < 2; ++ks) {
        bf16x8 af[4], bfr[4];
#pragma unroll
        for (int i = 0; i < 4; i++)
          af[i] = *(const bf16x8*)&As[wr * 64 + i * 16 + lx][ks * 32 + q4 * 8];
#pragma unroll
        for (int j = 0; j < 4; j++)
          bfr[j] = *(const bf16x8*)&Bs[wc * 64 + j * 16 + lx][ks * 32 + q4 * 8];
#pragma unroll
        for (int i = 0; i < 4; i++)
#pragma unroll
          for (int j = 0; j < 4; j++)
            acc[i][j] = __builtin_amdgcn_mfma_f32_16x16x32_bf16(af[i], bfr[j], acc[i][j], 0, 0, 0);
      }
    }

    // threshold scan -> per-row LDS lists (ballot-batched LDS atomics; all
    // 16 lanes of a q4-group share one row, so one atomic per active group)
#pragma unroll
    for (int i = 0; i < 4; i++)
#pragma unroll
      for (int j = 0; j < 4; j++)
#pragma unroll
        for (int r = 0; r < 4; r++) {
          const float v = acc[i][j][r];
          const unsigned long long mask = __ballot(v > TAU);
          if (v > TAU) {
            const int rloc = wr * 64 + i * 16 + q4 * 4 + r;  // 0..127
            const int idx = n0 + wc * 64 + j * 16 + lx;
            const unsigned int gm = (unsigned int)((mask >> (q4 * 16)) & 0xFFFFull);
            const int rank = __popc(gm & ((1u << lx) - 1u));
            const int leader = __ffs(gm) - 1;                // sub-lane in group
            int base = 0;
            if (lx == leader) base = atomicAdd(&lcnt[rloc], __popc(gm));
            base = __shfl(base, q4 * 16 + leader, 64);
            const int slot = base + rank;
            const unsigned int pk = (__float_as_uint(v) & 0xFFFF8000u) | (unsigned int)idx;
            if (slot < LCAP) {
              lds_list[rloc][slot] = pk;
            } else {  // ~impossible overflow: direct global append (correct)
              const int gs = atomicAdd(&cnt[m0 + rloc], 1);
              if (gs < CAP) cand[(long)(m0 + rloc) * CAP + gs] = pk;
            }
          }
        }
  }

  // flush: one global atomic per (row, block), outside the MFMA pipeline
  __syncthreads();
  if (t < 128) {
    const int n = lcnt[t];
    if (n > 0) {
      const int nk = n < LCAP ? n : LCAP;
      const int base = atomicAdd(&cnt[m0 + t], nk);
      for (int s = 0; s < nk; s++) {
        const int gs = base + s;
        if (gs < CAP) cand[(long)(m0 + t) * CAP + gs] = lds_list[t][s];
      }
    }
  }
}

// ---------------------------------------------------------------------------
// Refine: one wave per row. Coarse top-48 of the candidate list (monotone u32
// keys), exact fp32 rescore vs original keys, exact top-32 (jax tie-break:
// value desc then idx asc), softmax.
// ---------------------------------------------------------------------------
__global__ __launch_bounds__(256) void refine_kernel(const float* __restrict__ q,
                                                     const float* __restrict__ qinv,
                                                     const float* __restrict__ keys,
                                                     const float* __restrict__ kinv,
                                                     const int* __restrict__ cnt,
                                                     const unsigned int* __restrict__ cand,
                                                     float* __restrict__ w_top,
                                                     int* __restrict__ i_top) {
  const int row = blockIdx.x * 4 + (threadIdx.x >> 6);
  const int lane = threadIdx.x & 63;
  // q-hat fragment (4 k-dims per lane), same elementwise values as numpy's q_norm
  const float qs = qinv[row];
  float4 qh = ((const float4*)(q + (long)row * 256))[lane];
  qh.x *= qs; qh.y *= qs; qh.z *= qs; qh.w *= qs;
  int ncand = cnt[row];
  if (ncand > CAP) ncand = CAP;
  unsigned int loc[8];
#pragma unroll
  for (int s = 0; s < 8; s++) {
    const int c = s * 64 + lane;
    loc[s] = (c < ncand) ? cand[(long)row * CAP + c] : 0u;
  }
  // coarse top-48 by u32 key (monotone in bf16 sim; ties resolved by rescore)
  unsigned int mykey = 0;
  for (int it = 0; it < 48; ++it) {
    unsigned int best = loc[0];
#pragma unroll
    for (int s = 1; s < 8; s++) best = (loc[s] > best) ? loc[s] : best;
#pragma unroll
    for (int o = 32; o > 0; o >>= 1) {
      const unsigned int oth = __shfl_xor(best, o, 64);
      if (oth > best) best = oth;
    }
    if (best == 0u) break;  // wave-uniform: list exhausted
#pragma unroll
    for (int s = 0; s < 8; s++)
      if (loc[s] == best) loc[s] = 0;  // keys unique per row
    if (lane == it) mykey = best;
  }
  const int myidx = (int)(mykey & 0x7FFFu);
  // exact fp32 rescore of the (up to) 48
  float myexact = 0.0f;
  for (int c = 0; c < 48; ++c) {
    const unsigned int ky = __shfl(mykey, c, 64);
    if (ky == 0u) continue;  // wave-uniform branch
    const int idx = (int)(ky & 0x7FFFu);
    const float4 kv = ((const float4*)(keys + (long)idx * 256))[lane];
    float d = qh.x * kv.x + qh.y * kv.y + qh.z * kv.z + qh.w * kv.w;
    d = wave_sum(d);
    const float sim = d * kinv[idx];
    if (lane == c) myexact = sim;
  }
  // exact top-32 with jax tie-break (value desc, idx asc)
  unsigned long long ekey = (lane < 48 && mykey != 0u) ? pack_vi(myexact, myidx) : 0ULL;
  unsigned long long sel = 0;
  float maxv = 0.0f;
  for (int it = 0; it < 32; ++it) {
    unsigned long long best = ekey;
#pragma unroll
    for (int o = 32; o > 0; o >>= 1) {
      const unsigned long long oth = __shfl_xor(best, o, 64);
      if (oth > best) best = oth;
    }
    if (ekey == best) ekey = 0;
    if (lane == it) sel = best;
    if (it == 0) maxv = unpack_v(best);
  }
  float e = 0.0f;
  int oidx = 0;
  if (lane < 32) {
    e = expf(unpack_v(sel) - maxv);
    oidx = unpack_i(sel);
  }
  const float ssum = wave_sum(e);
  if (lane < 32) {
    w_top[(long)row * 32 + lane] = e / ssum;
    i_top[(long)row * 32 + lane] = oidx;
  }
}

// mem_out = sum_k w_k * values[idx_k]; h = bf16(mem_out * gate). One block/row.
__global__ __launch_bounds__(256) void gather_gate_kernel(const float* __restrict__ values,
                                                          const float* __restrict__ w_top,
                                                          const int* __restrict__ i_top,
                                                          const float* __restrict__ gate,
                                                          ushort_t* __restrict__ h) {
  __shared__ float w[32];
  __shared__ int ix[32];
  const int row = blockIdx.x;
  const int t = threadIdx.x;
  if (t < 32) {
    w[t] = w_top[(long)row * 32 + t];
    ix[t] = i_top[(long)row * 32 + t];
  }
  __syncthreads();
  float4 acc = make_float4(0.f, 0.f, 0.f, 0.f);
#pragma unroll 4
  for (int k = 0; k < 32; k++) {
    const float4 v = *(const float4*)(values + (long)ix[k] * 1024 + t * 4);
    const float wk = w[k];
    acc.x = fmaf(wk, v.x, acc.x);
    acc.y = fmaf(wk, v.y, acc.y);
    acc.z = fmaf(wk, v.z, acc.z);
    acc.w = fmaf(wk, v.w, acc.w);
  }
  const float4 g = *(const float4*)(gate + (long)row * 1024 + t * 4);
  ushort4 o;
  o.x = f2bf_rne(acc.x * g.x); o.y = f2bf_rne(acc.y * g.y);
  o.z = f2bf_rne(acc.z * g.z); o.w = f2bf_rne(acc.w * g.w);
  ((ushort4*)(h + (long)row * 1024))[t] = o;
}

extern "C" void kernel_launch(void* const* d_in, const int* in_sizes, int n_in,
                              void* d_out, int out_size, void* d_ws, size_t ws_size,
                              hipStream_t stream) {
  const float* x      = (const float*)d_in[0];  // [4,1024,1024]
  const float* keys   = (const float*)d_in[1];  // [32768,256]
  const float* values = (const float*)d_in[2];  // [32768,1024]
  const float* w_q    = (const float*)d_in[3];  // [256,1024]
  const float* w_gate = (const float*)d_in[4];  // [1024,1024]
  const float* w_out  = (const float*)d_in[5];  // [1024,1024]
  float* out = (float*)d_out;                   // [4,1024,1024]

  // workspace layout (4-byte units), ~51.5 MB total
  float* q        = (float*)d_ws;                   // 1,048,576
  float* qinv     = q + 1048576;                    // 4096
  float* kinv     = qinv + 4096;                    // 32768
  int*   cnt      = (int*)(kinv + 32768);           // 4096
  float* w_top    = (float*)(cnt + 4096);           // 131072
  int*   i_top    = (int*)(w_top + 131072);         // 131072
  ushort_t* qh    = (ushort_t*)(i_top + 131072);    // 524,288 f
  float* khf      = (float*)(qh + 1048576);         // 4,194,304 f region
  ushort_t* kh    = (ushort_t*)khf;                 //   [cast -> sims]
  ushort_t* hbf   = (ushort_t*)khf;                 //   alias: h bf16 [gather -> out GEMM]
  ushort_t* wo    = (ushort_t*)(khf + 2097152);     //   alias: w_out bf16 [after sims]
  float* gate     = khf + 4194304;                  // 4,194,304 f
  float* xbfr     = gate + 4194304;                 // 2,097,152 f region
  ushort_t* xb    = (ushort_t*)xbfr;                //   x bf16 [cast -> gate GEMM]
  unsigned int* cand = (unsigned int*)xbfr;         //   alias: candidates [sims -> refine]
  ushort_t* wg    = (ushort_t*)(xbfr + 2097152);    // 524,288 f

  zero_kernel<<<dim3(16), 256, 0, stream>>>(cnt);
  qgemm_kernel<<<dim3(4, 64), 256, 0, stream>>>(x, w_q, q);
  rownorm_inv_kernel<<<dim3(32768 / 4), 256, 0, stream>>>(keys, kinv);
  rownorm_inv_kernel<<<dim3(4096 / 4), 256, 0, stream>>>(q, qinv);
  cast_norm_kernel<<<dim3(4096 * 64 / 256), 256, 0, stream>>>(q, qinv, qh);
  cast_norm_kernel<<<dim3(32768 * 64 / 256), 256, 0, stream>>>(keys, kinv, kh);
  cast_bf16_kernel<<<dim3(4096), 256, 0, stream>>>(x, xb);
  cast_bf16_kernel<<<dim3(1024), 256, 0, stream>>>(w_gate, wg);
  // gate GEMM must precede sims (cand aliases xb)
  hgemm_bt_kernel<1><<<dim3(8, 32), 256, 0, stream>>>(xb, wg, gate, 4096, 1024, 1024);
  sims_coarse_kernel<<<dim3(1024), 256, 0, stream>>>(qh, kh, cnt, cand);
  // w_out cast must follow sims (wo aliases kh region)
  cast_bf16_kernel<<<dim3(1024), 256, 0, stream>>>(w_out, wo);
  refine_kernel<<<dim3(4096 / 4), 256, 0, stream>>>(q, qinv, keys, kinv, cnt, cand, w_top, i_top);
  gather_gate_kernel<<<dim3(4096), 256, 0, stream>>>(values, w_top, i_top, gate, hbf);
  hgemm_bt_kernel<0><<<dim3(8, 32), 256, 0, stream>>>(hbf, wo, out, 4096, 1024, 1024);
}

// Round 5
// 693.096 us; speedup vs baseline: 1.4448x; 1.2815x over previous
//
#include <hip/hip_runtime.h>
#include <cmath>
#include <cstdint>

// ---------------------------------------------------------------------------
// MemoryPlus: q = x@w_q^T; sims = norm(q)@norm(keys)^T; top-32 + softmax;
// mem_out = sum_k w_k * values[idx_k]; out = (mem_out * silu(x@w_gate^T)) @ w_out^T
//
// R9 (sims_coarse GEMM core only; selection math unchanged):
//  R7 counters: WRITE_SIZE still ~577 MB (~17 dwords/thread/chunk = half the
//  pa/pb prefetch array -> residual scratch spill of the reg-staging
//  pipeline), MfmaUtil 8%, 9M LDS bank-conflict cycles. All three are
//  properties of global->reg->ds_write staging. Fix = m97 structure:
//  global_load_lds width-16 DMA staging (no prefetch regs -> no spill, no
//  ds_write on the LDS port), linear [128][64] LDS tiles with XOR swizzle
//  applied BOTH sides (pre-swizzled global source + swizzled ds_read).
//  LDS 49.7 KB -> 3 blocks/CU. Scan: R7 ballot-batch + __any pre-skip.
// ---------------------------------------------------------------------------

typedef unsigned short ushort_t;
typedef __bf16 bf16x8 __attribute__((ext_vector_type(8)));
typedef float floatx4 __attribute__((ext_vector_type(4)));

#define TAU 0.16f
#define CAP 512
#define LCAP 32

#define GLD16(g, l)                                                      \
  __builtin_amdgcn_global_load_lds(                                      \
      (const __attribute__((address_space(1))) unsigned int*)(g),        \
      (__attribute__((address_space(3))) unsigned int*)(l), 16, 0, 0)

__device__ __forceinline__ float wave_sum(float v) {
#pragma unroll
  for (int o = 32; o > 0; o >>= 1) v += __shfl_xor(v, o, 64);
  return v;
}

__device__ __forceinline__ unsigned long long pack_vi(float v, int idx) {
  const unsigned int b = __float_as_uint(v);
  const unsigned int fk = (b & 0x80000000u) ? ~b : (b | 0x80000000u);
  return ((unsigned long long)fk << 32) | (unsigned int)(~idx);
}
__device__ __forceinline__ float unpack_v(unsigned long long k) {
  const unsigned int fk = (unsigned int)(k >> 32);
  const unsigned int b = (fk & 0x80000000u) ? (fk & 0x7FFFFFFFu) : ~fk;
  return __uint_as_float(b);
}
__device__ __forceinline__ int unpack_i(unsigned long long k) {
  return ~(int)(unsigned int)(k & 0xFFFFFFFFu);
}

__device__ __forceinline__ ushort_t f2bf_rne(float f) {
  const unsigned int u = __float_as_uint(f);
  return (ushort_t)((u + 0x7FFFu + ((u >> 16) & 1u)) >> 16);
}

__global__ __launch_bounds__(256) void zero_kernel(int* __restrict__ p) {
  p[blockIdx.x * 256 + threadIdx.x] = 0;
}

// inverse L2 norm of each 256-float row (matches F.normalize: 1/max(||v||,1e-12))
__global__ __launch_bounds__(256) void rownorm_inv_kernel(const float* __restrict__ rows,
                                                          float* __restrict__ inv) {
  const int r = blockIdx.x * 4 + (threadIdx.x >> 6);
  const int lane = threadIdx.x & 63;
  const float4 v = ((const float4*)(rows + (long)r * 256))[lane];
  float s = v.x * v.x + v.y * v.y + v.z * v.z + v.w * v.w;
  s = wave_sum(s);
  if (lane == 0) inv[r] = 1.0f / fmaxf(sqrtf(s), 1e-12f);
}

// out_bf16[r][c] = bf16(rows[r][c] * inv[r]), rows of 256. One float4 per thread.
__global__ __launch_bounds__(256) void cast_norm_kernel(const float* __restrict__ rows,
                                                        const float* __restrict__ inv,
                                                        ushort_t* __restrict__ out) {
  const long idx = (long)blockIdx.x * 256 + threadIdx.x;  // float4 index
  const int r = (int)(idx >> 6);
  const float s = inv[r];
  const float4 v = ((const float4*)rows)[idx];
  ushort4 o;
  o.x = f2bf_rne(v.x * s); o.y = f2bf_rne(v.y * s);
  o.z = f2bf_rne(v.z * s); o.w = f2bf_rne(v.w * s);
  ((ushort4*)out)[idx] = o;
}

// plain fp32 -> bf16 cast, one float4 per thread
__global__ __launch_bounds__(256) void cast_bf16_kernel(const float* __restrict__ in,
                                                        ushort_t* __restrict__ out) {
  const long idx = (long)blockIdx.x * 256 + threadIdx.x;
  const float4 v = ((const float4*)in)[idx];
  ushort4 o;
  o.x = f2bf_rne(v.x); o.y = f2bf_rne(v.y);
  o.z = f2bf_rne(v.z); o.w = f2bf_rne(v.w);
  ((ushort4*)out)[idx] = o;
}

// fp32 q GEMM: C[4096,256] = A[4096,1024] @ B[256,1024]^T. 64x64 tile,
// 4x4/thread, BK=32. grid (4,64)=256 blocks (q feeds exact rescore: fp32).
__global__ __launch_bounds__(256) void qgemm_kernel(const float* __restrict__ A,
                                                    const float* __restrict__ B,
                                                    float* __restrict__ C) {
  __shared__ float As[32][64];
  __shared__ float Bs[32][64];
  const int t = threadIdx.x;
  const int tx = t & 15, ty = t >> 4;
  const int m0 = blockIdx.y * 64, n0 = blockIdx.x * 64;
  const int lr = t >> 2;          // staged row 0..63 (4 threads/row)
  const int lk = (t & 3) * 8;     // k offset 0,8,16,24
  const float* Ap = A + (long)(m0 + lr) * 1024 + lk;
  const float* Bp = B + (long)(n0 + lr) * 1024 + lk;
  float acc[4][4] = {};
  for (int kc = 0; kc < 1024; kc += 32) {
    const float4 a0 = *(const float4*)(Ap + kc);
    const float4 a1 = *(const float4*)(Ap + kc + 4);
    const float4 b0 = *(const float4*)(Bp + kc);
    const float4 b1 = *(const float4*)(Bp + kc + 4);
    __syncthreads();
    As[lk + 0][lr] = a0.x; As[lk + 1][lr] = a0.y; As[lk + 2][lr] = a0.z; As[lk + 3][lr] = a0.w;
    As[lk + 4][lr] = a1.x; As[lk + 5][lr] = a1.y; As[lk + 6][lr] = a1.z; As[lk + 7][lr] = a1.w;
    Bs[lk + 0][lr] = b0.x; Bs[lk + 1][lr] = b0.y; Bs[lk + 2][lr] = b0.z; Bs[lk + 3][lr] = b0.w;
    Bs[lk + 4][lr] = b1.x; Bs[lk + 5][lr] = b1.y; Bs[lk + 6][lr] = b1.z; Bs[lk + 7][lr] = b1.w;
    __syncthreads();
#pragma unroll
    for (int kk = 0; kk < 32; kk++) {
      const float4 a = *(const float4*)&As[kk][ty * 4];
      const float4 b = *(const float4*)&Bs[kk][tx * 4];
      const float av[4] = {a.x, a.y, a.z, a.w};
      const float bv[4] = {b.x, b.y, b.z, b.w};
#pragma unroll
      for (int i = 0; i < 4; i++)
#pragma unroll
        for (int j = 0; j < 4; j++) acc[i][j] = fmaf(av[i], bv[j], acc[i][j]);
    }
  }
#pragma unroll
  for (int i = 0; i < 4; i++) {
    float* Cr = C + (long)(m0 + ty * 4 + i) * 256 + n0 + tx * 4;
    *(float4*)Cr = make_float4(acc[i][0], acc[i][1], acc[i][2], acc[i][3]);
  }
}

// bf16 MFMA GEMM: C[M,N] fp32 = A[M,K]bf16 @ B[N,K]bf16^T. 128x128 tile,
// 4 waves each 64x64 (4x4 of 16x16x32), BK=64, register-prefetch pipeline.
template <int EP>  // 0 = none, 1 = silu
__global__ __launch_bounds__(256, 2) void hgemm_bt_kernel(const ushort_t* __restrict__ A,
                                                          const ushort_t* __restrict__ B,
                                                          float* __restrict__ C,
                                                          int M, int N, int K) {
  __shared__ ushort_t As[128][72];
  __shared__ ushort_t Bs[128][72];
  const int t = threadIdx.x;
  const int m0 = blockIdx.y * 128, n0 = blockIdx.x * 128;
  const int lane = t & 63, wv = t >> 6;
  const int wr = wv >> 1, wc = wv & 1;
  const int q4 = lane >> 4, lx = lane & 15;
  const int r0 = t >> 3, sg = t & 7;
  const floatx4 vzero = {0.f, 0.f, 0.f, 0.f};
  floatx4 acc[4][4];
#pragma unroll
  for (int i = 0; i < 4; i++)
#pragma unroll
    for (int j = 0; j < 4; j++) acc[i][j] = vzero;

  uint4 pa[4], pb[4];
#pragma unroll
  for (int it = 0; it < 4; it++) {
    const int row = it * 32 + r0;
    pa[it] = *(const uint4*)(A + (long)(m0 + row) * K + sg * 8);
    pb[it] = *(const uint4*)(B + (long)(n0 + row) * K + sg * 8);
  }
  const int NC = K >> 6;
  for (int c = 0; c < NC; ++c) {
    __syncthreads();
#pragma unroll
    for (int it = 0; it < 4; it++) {
      const int row = it * 32 + r0;
      *(uint4*)&As[row][sg * 8] = pa[it];
      *(uint4*)&Bs[row][sg * 8] = pb[it];
    }
    if (c + 1 < NC) {
      const int c0 = (c + 1) * 64;
#pragma unroll
      for (int it = 0; it < 4; it++) {
        const int row = it * 32 + r0;
        pa[it] = *(const uint4*)(A + (long)(m0 + row) * K + c0 + sg * 8);
        pb[it] = *(const uint4*)(B + (long)(n0 + row) * K + c0 + sg * 8);
      }
    }
    __syncthreads();
#pragma unroll
    for (int ks = 0; ks < 2; ++ks) {
      bf16x8 af[4], bfr[4];
#pragma unroll
      for (int i = 0; i < 4; i++)
        af[i] = *(const bf16x8*)&As[wr * 64 + i * 16 + lx][ks * 32 + q4 * 8];
#pragma unroll
      for (int j = 0; j < 4; j++)
        bfr[j] = *(const bf16x8*)&Bs[wc * 64 + j * 16 + lx][ks * 32 + q4 * 8];
#pragma unroll
      for (int i = 0; i < 4; i++)
#pragma unroll
        for (int j = 0; j < 4; j++)
          acc[i][j] = __builtin_amdgcn_mfma_f32_16x16x32_bf16(af[i], bfr[j], acc[i][j], 0, 0, 0);
    }
  }
#pragma unroll
  for (int i = 0; i < 4; i++)
#pragma unroll
    for (int j = 0; j < 4; j++) {
      const int col = n0 + wc * 64 + j * 16 + lx;
#pragma unroll
      for (int r = 0; r < 4; r++) {
        const int row = m0 + wr * 64 + i * 16 + q4 * 4 + r;
        float v = acc[i][j][r];
        if (EP == 1) v = v / (1.0f + expf(-v));  // silu
        C[(long)row * N + col] = v;
      }
    }
}

// ---------------------------------------------------------------------------
// Coarse sims: bf16 MFMA GEMM, block = 128 q-rows x 1024 keys (8 tiles of
// 128), K=256 in 4 chunks of 64. Staging via global_load_lds width-16 into
// linear [128][64] bf16 tiles (128 B rows); XOR swizzle (byte ^= (row&7)<<4
// within each 128 B chunk) applied on the global SOURCE address and on the
// ds_read address (both-sides rule). Scan: per-row LDS lists, ballot-batched
// LDS atomics with a wave-uniform __any pre-skip; one global atomic per
// (row, block) at kernel end. Overflow beyond LCAP -> direct global append.
// ---------------------------------------------------------------------------
__global__ __launch_bounds__(256, 2) void sims_coarse_kernel(const ushort_t* __restrict__ qh,
                                                             const ushort_t* __restrict__ kh,
                                                             int* __restrict__ cnt,
                                                             unsigned int* __restrict__ cand) {
  __shared__ __align__(16) ushort_t AsL[128 * 64];
  __shared__ __align__(16) ushort_t BsL[128 * 64];
  __shared__ unsigned int lds_list[128][LCAP];
  __shared__ int lcnt[128];
  const int t = threadIdx.x;
  // XCD-grouped bijective swizzle (1024 blocks, 8 XCDs, nwg%8==0):
  const int bid = blockIdx.x;
  const int xcd = bid & 7;
  const int jj = bid >> 3;              // 0..127 within XCD
  const int cs = xcd * 4 + (jj >> 5);   // key-slice 0..31 (4 per XCD)
  const int rb = jj & 31;               // q-row-block 0..31
  const int m0 = rb * 128;
  const int lane = t & 63, wv = t >> 6;
  const int wr = wv >> 1, wc = wv & 1;
  const int q4 = lane >> 4, lx = lane & 15;

  if (t < 128) lcnt[t] = 0;  // ordered before first scan by chunk-loop barriers

  // DMA lane geometry: one gload_lds instr = 64 lanes x 16 B = 8 rows x 128 B.
  // Linear dest (HW: base + lane*16); source byte pre-swizzled so that
  // LDS[row][w] = G[row][w ^ ((row&7)<<4)].
  const int lr8 = lane >> 3;                         // sub-row 0..7
  const int lsw = ((lane & 7) * 16) ^ (lr8 << 4);    // swizzled byte in 128B
  const char* qbase = (const char*)qh;
  const char* kbase = (const char*)kh;
  char* AsB = (char*)AsL;
  char* BsB = (char*)BsL;

  for (int tile = 0; tile < 8; ++tile) {
    const int n0 = cs * 1024 + tile * 128;
    const floatx4 vzero = {0.f, 0.f, 0.f, 0.f};
    floatx4 acc[4][4];
#pragma unroll
    for (int i = 0; i < 4; i++)
#pragma unroll
      for (int j = 0; j < 4; j++) acc[i][j] = vzero;

    for (int chunk = 0; chunk < 4; ++chunk) {
      __syncthreads();  // prior tile/chunk LDS reads complete
      const int cb = chunk * 128;  // byte offset within 512 B source row
#pragma unroll
      for (int u = 0; u < 4; u++) {
        const int s = wv * 4 + u;            // staging instr 0..15
        const int row = s * 8 + lr8;         // tile-relative row 0..127
        GLD16(qbase + ((long)(m0 + row) << 9) + cb + lsw, AsB + s * 1024);
        GLD16(kbase + ((long)(n0 + row) << 9) + cb + lsw, BsB + s * 1024);
      }
      __syncthreads();  // vmcnt drain -> staged data visible
#pragma unroll
      for (int ks = 0; ks < 2; ++ks) {
        bf16x8 af[4], bfr[4];
        const int cbyte = (ks * 64 + q4 * 16) ^ ((lx & 7) << 4);
#pragma unroll
        for (int i = 0; i < 4; i++)
          af[i] = *(const bf16x8*)(AsB + (wr * 64 + i * 16 + lx) * 128 + cbyte);
#pragma unroll
        for (int j = 0; j < 4; j++)
          bfr[j] = *(const bf16x8*)(BsB + (wc * 64 + j * 16 + lx) * 128 + cbyte);
#pragma unroll
        for (int i = 0; i < 4; i++)
#pragma unroll
          for (int j = 0; j < 4; j++)
            acc[i][j] = __builtin_amdgcn_mfma_f32_16x16x32_bf16(af[i], bfr[j], acc[i][j], 0, 0, 0);
      }
    }

    // threshold scan -> per-row LDS lists. Wave-uniform __any pre-skip per
    // 16-value group (~73% skipped), then ballot-batched LDS atomics (one
    // atomic per active 16-lane group).
#pragma unroll
    for (int i = 0; i < 4; i++)
#pragma unroll
      for (int j = 0; j < 4; j++) {
        const float m01 = fmaxf(acc[i][j][0], acc[i][j][1]);
        const float m23 = fmaxf(acc[i][j][2], acc[i][j][3]);
        if (__any(fmaxf(m01, m23) > TAU)) {
#pragma unroll
          for (int r = 0; r < 4; r++) {
            const float v = acc[i][j][r];
            const unsigned long long mask = __ballot(v > TAU);
            if (v > TAU) {
              const int rloc = wr * 64 + i * 16 + q4 * 4 + r;  // 0..127
              const int idx = n0 + wc * 64 + j * 16 + lx;
              const unsigned int gm = (unsigned int)((mask >> (q4 * 16)) & 0xFFFFull);
              const int rank = __popc(gm & ((1u << lx) - 1u));
              const int leader = __ffs(gm) - 1;                // sub-lane in group
              int base = 0;
              if (lx == leader) base = atomicAdd(&lcnt[rloc], __popc(gm));
              base = __shfl(base, q4 * 16 + leader, 64);
              const int slot = base + rank;
              const unsigned int pk = (__float_as_uint(v) & 0xFFFF8000u) | (unsigned int)idx;
              if (slot < LCAP) {
                lds_list[rloc][slot] = pk;
              } else {  // ~impossible overflow: direct global append (correct)
                const int gs = atomicAdd(&cnt[m0 + rloc], 1);
                if (gs < CAP) cand[(long)(m0 + rloc) * CAP + gs] = pk;
              }
            }
          }
        }
      }
  }

  // flush: one global atomic per (row, block), outside the MFMA pipeline
  __syncthreads();
  if (t < 128) {
    const int n = lcnt[t];
    if (n > 0) {
      const int nk = n < LCAP ? n : LCAP;
      const int base = atomicAdd(&cnt[m0 + t], nk);
      for (int s = 0; s < nk; s++) {
        const int gs = base + s;
        if (gs < CAP) cand[(long)(m0 + t) * CAP + gs] = lds_list[t][s];
      }
    }
  }
}

// ---------------------------------------------------------------------------
// Refine: one wave per row. Coarse top-48 of the candidate list (monotone u32
// keys), exact fp32 rescore vs original keys, exact top-32 (jax tie-break:
// value desc then idx asc), softmax.
// ---------------------------------------------------------------------------
__global__ __launch_bounds__(256) void refine_kernel(const float* __restrict__ q,
                                                     const float* __restrict__ qinv,
                                                     const float* __restrict__ keys,
                                                     const float* __restrict__ kinv,
                                                     const int* __restrict__ cnt,
                                                     const unsigned int* __restrict__ cand,
                                                     float* __restrict__ w_top,
                                                     int* __restrict__ i_top) {
  const int row = blockIdx.x * 4 + (threadIdx.x >> 6);
  const int lane = threadIdx.x & 63;
  // q-hat fragment (4 k-dims per lane), same elementwise values as numpy's q_norm
  const float qs = qinv[row];
  float4 qh = ((const float4*)(q + (long)row * 256))[lane];
  qh.x *= qs; qh.y *= qs; qh.z *= qs; qh.w *= qs;
  int ncand = cnt[row];
  if (ncand > CAP) ncand = CAP;
  unsigned int loc[8];
#pragma unroll
  for (int s = 0; s < 8; s++) {
    const int c = s * 64 + lane;
    loc[s] = (c < ncand) ? cand[(long)row * CAP + c] : 0u;
  }
  // coarse top-48 by u32 key (monotone in bf16 sim; ties resolved by rescore)
  unsigned int mykey = 0;
  for (int it = 0; it < 48; ++it) {
    unsigned int best = loc[0];
#pragma unroll
    for (int s = 1; s < 8; s++) best = (loc[s] > best) ? loc[s] : best;
#pragma unroll
    for (int o = 32; o > 0; o >>= 1) {
      const unsigned int oth = __shfl_xor(best, o, 64);
      if (oth > best) best = oth;
    }
    if (best == 0u) break;  // wave-uniform: list exhausted
#pragma unroll
    for (int s = 0; s < 8; s++)
      if (loc[s] == best) loc[s] = 0;  // keys unique per row
    if (lane == it) mykey = best;
  }
  const int myidx = (int)(mykey & 0x7FFFu);
  // exact fp32 rescore of the (up to) 48
  float myexact = 0.0f;
  for (int c = 0; c < 48; ++c) {
    const unsigned int ky = __shfl(mykey, c, 64);
    if (ky == 0u) continue;  // wave-uniform branch
    const int idx = (int)(ky & 0x7FFFu);
    const float4 kv = ((const float4*)(keys + (long)idx * 256))[lane];
    float d = qh.x * kv.x + qh.y * kv.y + qh.z * kv.z + qh.w * kv.w;
    d = wave_sum(d);
    const float sim = d * kinv[idx];
    if (lane == c) myexact = sim;
  }
  // exact top-32 with jax tie-break (value desc, idx asc)
  unsigned long long ekey = (lane < 48 && mykey != 0u) ? pack_vi(myexact, myidx) : 0ULL;
  unsigned long long sel = 0;
  float maxv = 0.0f;
  for (int it = 0; it < 32; ++it) {
    unsigned long long best = ekey;
#pragma unroll
    for (int o = 32; o > 0; o >>= 1) {
      const unsigned long long oth = __shfl_xor(best, o, 64);
      if (oth > best) best = oth;
    }
    if (ekey == best) ekey = 0;
    if (lane == it) sel = best;
    if (it == 0) maxv = unpack_v(best);
  }
  float e = 0.0f;
  int oidx = 0;
  if (lane < 32) {
    e = expf(unpack_v(sel) - maxv);
    oidx = unpack_i(sel);
  }
  const float ssum = wave_sum(e);
  if (lane < 32) {
    w_top[(long)row * 32 + lane] = e / ssum;
    i_top[(long)row * 32 + lane] = oidx;
  }
}

// mem_out = sum_k w_k * values[idx_k]; h = bf16(mem_out * gate). One block/row.
__global__ __launch_bounds__(256) void gather_gate_kernel(const float* __restrict__ values,
                                                          const float* __restrict__ w_top,
                                                          const int* __restrict__ i_top,
                                                          const float* __restrict__ gate,
                                                          ushort_t* __restrict__ h) {
  __shared__ float w[32];
  __shared__ int ix[32];
  const int row = blockIdx.x;
  const int t = threadIdx.x;
  if (t < 32) {
    w[t] = w_top[(long)row * 32 + t];
    ix[t] = i_top[(long)row * 32 + t];
  }
  __syncthreads();
  float4 acc = make_float4(0.f, 0.f, 0.f, 0.f);
#pragma unroll 4
  for (int k = 0; k < 32; k++) {
    const float4 v = *(const float4*)(values + (long)ix[k] * 1024 + t * 4);
    const float wk = w[k];
    acc.x = fmaf(wk, v.x, acc.x);
    acc.y = fmaf(wk, v.y, acc.y);
    acc.z = fmaf(wk, v.z, acc.z);
    acc.w = fmaf(wk, v.w, acc.w);
  }
  const float4 g = *(const float4*)(gate + (long)row * 1024 + t * 4);
  ushort4 o;
  o.x = f2bf_rne(acc.x * g.x); o.y = f2bf_rne(acc.y * g.y);
  o.z = f2bf_rne(acc.z * g.z); o.w = f2bf_rne(acc.w * g.w);
  ((ushort4*)(h + (long)row * 1024))[t] = o;
}

extern "C" void kernel_launch(void* const* d_in, const int* in_sizes, int n_in,
                              void* d_out, int out_size, void* d_ws, size_t ws_size,
                              hipStream_t stream) {
  const float* x      = (const float*)d_in[0];  // [4,1024,1024]
  const float* keys   = (const float*)d_in[1];  // [32768,256]
  const float* values = (const float*)d_in[2];  // [32768,1024]
  const float* w_q    = (const float*)d_in[3];  // [256,1024]
  const float* w_gate = (const float*)d_in[4];  // [1024,1024]
  const float* w_out  = (const float*)d_in[5];  // [1024,1024]
  float* out = (float*)d_out;                   // [4,1024,1024]

  // workspace layout (4-byte units), ~51.5 MB total
  float* q        = (float*)d_ws;                   // 1,048,576
  float* qinv     = q + 1048576;                    // 4096
  float* kinv     = qinv + 4096;                    // 32768
  int*   cnt      = (int*)(kinv + 32768);           // 4096
  float* w_top    = (float*)(cnt + 4096);           // 131072
  int*   i_top    = (int*)(w_top + 131072);         // 131072
  ushort_t* qh    = (ushort_t*)(i_top + 131072);    // 524,288 f
  float* khf      = (float*)(qh + 1048576);         // 4,194,304 f region
  ushort_t* kh    = (ushort_t*)khf;                 //   [cast -> sims]
  ushort_t* hbf   = (ushort_t*)khf;                 //   alias: h bf16 [gather -> out GEMM]
  ushort_t* wo    = (ushort_t*)(khf + 2097152);     //   alias: w_out bf16 [after sims]
  float* gate     = khf + 4194304;                  // 4,194,304 f
  float* xbfr     = gate + 4194304;                 // 2,097,152 f region
  ushort_t* xb    = (ushort_t*)xbfr;                //   x bf16 [cast -> gate GEMM]
  unsigned int* cand = (unsigned int*)xbfr;         //   alias: candidates [sims -> refine]
  ushort_t* wg    = (ushort_t*)(xbfr + 2097152);    // 524,288 f

  zero_kernel<<<dim3(16), 256, 0, stream>>>(cnt);
  qgemm_kernel<<<dim3(4, 64), 256, 0, stream>>>(x, w_q, q);
  rownorm_inv_kernel<<<dim3(32768 / 4), 256, 0, stream>>>(keys, kinv);
  rownorm_inv_kernel<<<dim3(4096 / 4), 256, 0, stream>>>(q, qinv);
  cast_norm_kernel<<<dim3(4096 * 64 / 256), 256, 0, stream>>>(q, qinv, qh);
  cast_norm_kernel<<<dim3(32768 * 64 / 256), 256, 0, stream>>>(keys, kinv, kh);
  cast_bf16_kernel<<<dim3(4096), 256, 0, stream>>>(x, xb);
  cast_bf16_kernel<<<dim3(1024), 256, 0, stream>>>(w_gate, wg);
  // gate GEMM must precede sims (cand aliases xb)
  hgemm_bt_kernel<1><<<dim3(8, 32), 256, 0, stream>>>(xb, wg, gate, 4096, 1024, 1024);
  sims_coarse_kernel<<<dim3(1024), 256, 0, stream>>>(qh, kh, cnt, cand);
  // w_out cast must follow sims (wo aliases kh region)
  cast_bf16_kernel<<<dim3(1024), 256, 0, stream>>>(w_out, wo);
  refine_kernel<<<dim3(4096 / 4), 256, 0, stream>>>(q, qinv, keys, kinv, cnt, cand, w_top, i_top);
  gather_gate_kernel<<<dim3(4096), 256, 0, stream>>>(values, w_top, i_top, gate, hbf);
  hgemm_bt_kernel<0><<<dim3(8, 32), 256, 0, stream>>>(hbf, wo, out, 4096, 1024, 1024);
}

// Round 7
// 688.779 us; speedup vs baseline: 1.4539x; 1.0063x over previous
//
#include <hip/hip_runtime.h>
#include <cmath>
#include <cstdint>

// ---------------------------------------------------------------------------
// MemoryPlus: q = x@w_q^T; sims = norm(q)@norm(keys)^T; top-32 + softmax;
// mem_out = sum_k w_k * values[idx_k]; out = (mem_out * silu(x@w_gate^T)) @ w_out^T
//
// R10 (on top of R9's DMA-staged sims, which fixed the scratch spill:
// WRITE 577->6.7 MB, sims 342->140 us):
//  (a) sims occupancy: LCAP 32->15 -> LDS exactly 40 KB -> 4 blocks/CU
//      (was 48.5 KB -> 3), grid 1024 = exactly one dispatch round (no tail);
//      __launch_bounds__(256,4) (VGPR=104 <= 128, no spill risk).
//  (b) launch-count 14->11: rownorm+cast fused (keys, q; also -40 MB
//      re-reads), cnt-zeroing fused into x-cast. ~10 us/launch graph-node
//      overhead suspected in the constant ~553 us non-sims remainder.
//  (c) qgemm 64x64/256blk (1/CU) -> 32x64/512blk (2/CU); identical
//      K-accumulation order -> bit-identical q.
// R11: identical resubmission of R10 (bench infra failed; no counters).
// ---------------------------------------------------------------------------

typedef unsigned short ushort_t;
typedef __bf16 bf16x8 __attribute__((ext_vector_type(8)));
typedef float floatx4 __attribute__((ext_vector_type(4)));

#define TAU 0.16f
#define CAP 512
#define LCAP 15

#define GLD16(g, l)                                                      \
  __builtin_amdgcn_global_load_lds(                                      \
      (const __attribute__((address_space(1))) unsigned int*)(g),        \
      (__attribute__((address_space(3))) unsigned int*)(l), 16, 0, 0)

__device__ __forceinline__ float wave_sum(float v) {
#pragma unroll
  for (int o = 32; o > 0; o >>= 1) v += __shfl_xor(v, o, 64);
  return v;
}

__device__ __forceinline__ unsigned long long pack_vi(float v, int idx) {
  const unsigned int b = __float_as_uint(v);
  const unsigned int fk = (b & 0x80000000u) ? ~b : (b | 0x80000000u);
  return ((unsigned long long)fk << 32) | (unsigned int)(~idx);
}
__device__ __forceinline__ float unpack_v(unsigned long long k) {
  const unsigned int fk = (unsigned int)(k >> 32);
  const unsigned int b = (fk & 0x80000000u) ? (fk & 0x7FFFFFFFu) : ~fk;
  return __uint_as_float(b);
}
__device__ __forceinline__ int unpack_i(unsigned long long k) {
  return ~(int)(unsigned int)(k & 0xFFFFFFFFu);
}

__device__ __forceinline__ ushort_t f2bf_rne(float f) {
  const unsigned int u = __float_as_uint(f);
  return (ushort_t)((u + 0x7FFFu + ((u >> 16) & 1u)) >> 16);
}

// fused: inverse L2 norm of each 256-float row + normalized bf16 cast.
// One wave per row; wave_sum value identical on all lanes (same butterfly).
__global__ __launch_bounds__(256) void rownorm_cast_kernel(const float* __restrict__ rows,
                                                           float* __restrict__ inv,
                                                           ushort_t* __restrict__ out) {
  const int r = blockIdx.x * 4 + (threadIdx.x >> 6);
  const int lane = threadIdx.x & 63;
  const float4 v = ((const float4*)(rows + (long)r * 256))[lane];
  float s = v.x * v.x + v.y * v.y + v.z * v.z + v.w * v.w;
  s = wave_sum(s);
  const float sc = 1.0f / fmaxf(sqrtf(s), 1e-12f);
  if (lane == 0) inv[r] = sc;
  ushort4 o;
  o.x = f2bf_rne(v.x * sc); o.y = f2bf_rne(v.y * sc);
  o.z = f2bf_rne(v.z * sc); o.w = f2bf_rne(v.w * sc);
  ((ushort4*)(out + (long)r * 256))[lane] = o;
}

// plain fp32 -> bf16 cast, one float4 per thread
__global__ __launch_bounds__(256) void cast_bf16_kernel(const float* __restrict__ in,
                                                        ushort_t* __restrict__ out) {
  const long idx = (long)blockIdx.x * 256 + threadIdx.x;
  const float4 v = ((const float4*)in)[idx];
  ushort4 o;
  o.x = f2bf_rne(v.x); o.y = f2bf_rne(v.y);
  o.z = f2bf_rne(v.z); o.w = f2bf_rne(v.w);
  ((ushort4*)out)[idx] = o;
}

// x cast + fused cnt zeroing (cnt untouched until sims, which runs later)
__global__ __launch_bounds__(256) void cast_bf16_zero_kernel(const float* __restrict__ in,
                                                             ushort_t* __restrict__ out,
                                                             int* __restrict__ cnt) {
  if (blockIdx.x < 16) cnt[blockIdx.x * 256 + threadIdx.x] = 0;
  const long idx = (long)blockIdx.x * 256 + threadIdx.x;
  const float4 v = ((const float4*)in)[idx];
  ushort4 o;
  o.x = f2bf_rne(v.x); o.y = f2bf_rne(v.y);
  o.z = f2bf_rne(v.z); o.w = f2bf_rne(v.w);
  ((ushort4*)out)[idx] = o;
}

// fp32 q GEMM: C[4096,256] = A[4096,1024] @ B[256,1024]^T. 32x64 tile,
// 2x4/thread, BK=32, grid (4,128)=512 blocks (2/CU). Same K-order as the
// 64x64 version -> bit-identical C (q feeds exact rescore: fp32).
__global__ __launch_bounds__(256) void qgemm_kernel(const float* __restrict__ A,
                                                    const float* __restrict__ B,
                                                    float* __restrict__ C) {
  __shared__ float As[32][32];
  __shared__ float Bs[32][64];
  const int t = threadIdx.x;
  const int tx = t & 15, ty = t >> 4;
  const int m0 = blockIdx.y * 32, n0 = blockIdx.x * 64;
  const int lrA = t >> 3;          // A row 0..31 (8 threads/row)
  const int lkA = (t & 7) * 4;     // k offset 0,4,..,28
  const int lrB = t >> 2;          // B row 0..63 (4 threads/row)
  const int lkB = (t & 3) * 8;     // k offset 0,8,16,24
  const float* Ap = A + (long)(m0 + lrA) * 1024 + lkA;
  const float* Bp = B + (long)(n0 + lrB) * 1024 + lkB;
  float acc[2][4] = {};
  for (int kc = 0; kc < 1024; kc += 32) {
    const float4 a0 = *(const float4*)(Ap + kc);
    const float4 b0 = *(const float4*)(Bp + kc);
    const float4 b1 = *(const float4*)(Bp + kc + 4);
    __syncthreads();
    As[lkA + 0][lrA] = a0.x; As[lkA + 1][lrA] = a0.y;
    As[lkA + 2][lrA] = a0.z; As[lkA + 3][lrA] = a0.w;
    Bs[lkB + 0][lrB] = b0.x; Bs[lkB + 1][lrB] = b0.y; Bs[lkB + 2][lrB] = b0.z; Bs[lkB + 3][lrB] = b0.w;
    Bs[lkB + 4][lrB] = b1.x; Bs[lkB + 5][lrB] = b1.y; Bs[lkB + 6][lrB] = b1.z; Bs[lkB + 7][lrB] = b1.w;
    __syncthreads();
#pragma unroll
    for (int kk = 0; kk < 32; kk++) {
      const float2 a = *(const float2*)&As[kk][ty * 2];
      const float4 b = *(const float4*)&Bs[kk][tx * 4];
      const float av[2] = {a.x, a.y};
      const float bv[4] = {b.x, b.y, b.z, b.w};
#pragma unroll
      for (int i = 0; i < 2; i++)
#pragma unroll
        for (int j = 0; j < 4; j++) acc[i][j] = fmaf(av[i], bv[j], acc[i][j]);
    }
  }
#pragma unroll
  for (int i = 0; i < 2; i++) {
    float* Cr = C + (long)(m0 + ty * 2 + i) * 256 + n0 + tx * 4;
    *(float4*)Cr = make_float4(acc[i][0], acc[i][1], acc[i][2], acc[i][3]);
  }
}

// bf16 MFMA GEMM: C[M,N] fp32 = A[M,K]bf16 @ B[N,K]bf16^T. 128x128 tile,
// 4 waves each 64x64 (4x4 of 16x16x32), BK=64, register-prefetch pipeline.
template <int EP>  // 0 = none, 1 = silu
__global__ __launch_bounds__(256, 2) void hgemm_bt_kernel(const ushort_t* __restrict__ A,
                                                          const ushort_t* __restrict__ B,
                                                          float* __restrict__ C,
                                                          int M, int N, int K) {
  __shared__ ushort_t As[128][72];
  __shared__ ushort_t Bs[128][72];
  const int t = threadIdx.x;
  const int m0 = blockIdx.y * 128, n0 = blockIdx.x * 128;
  const int lane = t & 63, wv = t >> 6;
  const int wr = wv >> 1, wc = wv & 1;
  const int q4 = lane >> 4, lx = lane & 15;
  const int r0 = t >> 3, sg = t & 7;
  const floatx4 vzero = {0.f, 0.f, 0.f, 0.f};
  floatx4 acc[4][4];
#pragma unroll
  for (int i = 0; i < 4; i++)
#pragma unroll
    for (int j = 0; j < 4; j++) acc[i][j] = vzero;

  uint4 pa[4], pb[4];
#pragma unroll
  for (int it = 0; it < 4; it++) {
    const int row = it * 32 + r0;
    pa[it] = *(const uint4*)(A + (long)(m0 + row) * K + sg * 8);
    pb[it] = *(const uint4*)(B + (long)(n0 + row) * K + sg * 8);
  }
  const int NC = K >> 6;
  for (int c = 0; c < NC; ++c) {
    __syncthreads();
#pragma unroll
    for (int it = 0; it < 4; it++) {
      const int row = it * 32 + r0;
      *(uint4*)&As[row][sg * 8] = pa[it];
      *(uint4*)&Bs[row][sg * 8] = pb[it];
    }
    if (c + 1 < NC) {
      const int c0 = (c + 1) * 64;
#pragma unroll
      for (int it = 0; it < 4; it++) {
        const int row = it * 32 + r0;
        pa[it] = *(const uint4*)(A + (long)(m0 + row) * K + c0 + sg * 8);
        pb[it] = *(const uint4*)(B + (long)(n0 + row) * K + c0 + sg * 8);
      }
    }
    __syncthreads();
#pragma unroll
    for (int ks = 0; ks < 2; ++ks) {
      bf16x8 af[4], bfr[4];
#pragma unroll
      for (int i = 0; i < 4; i++)
        af[i] = *(const bf16x8*)&As[wr * 64 + i * 16 + lx][ks * 32 + q4 * 8];
#pragma unroll
      for (int j = 0; j < 4; j++)
        bfr[j] = *(const bf16x8*)&Bs[wc * 64 + j * 16 + lx][ks * 32 + q4 * 8];
#pragma unroll
      for (int i = 0; i < 4; i++)
#pragma unroll
        for (int j = 0; j < 4; j++)
          acc[i][j] = __builtin_amdgcn_mfma_f32_16x16x32_bf16(af[i], bfr[j], acc[i][j], 0, 0, 0);
    }
  }
#pragma unroll
  for (int i = 0; i < 4; i++)
#pragma unroll
    for (int j = 0; j < 4; j++) {
      const int col = n0 + wc * 64 + j * 16 + lx;
#pragma unroll
      for (int r = 0; r < 4; r++) {
        const int row = m0 + wr * 64 + i * 16 + q4 * 4 + r;
        float v = acc[i][j][r];
        if (EP == 1) v = v / (1.0f + expf(-v));  // silu
        C[(long)row * N + col] = v;
      }
    }
}

// ---------------------------------------------------------------------------
// Coarse sims: bf16 MFMA GEMM, block = 128 q-rows x 1024 keys (8 tiles of
// 128), K=256 in 4 chunks of 64. Staging via global_load_lds width-16 into
// linear [128][64] bf16 tiles; XOR swizzle applied on global SOURCE address
// and ds_read address (both-sides rule). Scan: per-row LDS lists (LCAP=15;
// overflow -> direct global append, order-independent for refine), ballot-
// batched LDS atomics with __any pre-skip; one global atomic per (row,block)
// flush. LDS exactly 40 KB -> 4 blocks/CU; grid 1024 = one dispatch round.
// ---------------------------------------------------------------------------
__global__ __launch_bounds__(256, 4) void sims_coarse_kernel(const ushort_t* __restrict__ qh,
                                                             const ushort_t* __restrict__ kh,
                                                             int* __restrict__ cnt,
                                                             unsigned int* __restrict__ cand) {
  __shared__ __align__(16) ushort_t AsL[128 * 64];
  __shared__ __align__(16) ushort_t BsL[128 * 64];
  __shared__ unsigned int lds_list[128][LCAP];
  __shared__ int lcnt[128];
  const int t = threadIdx.x;
  // XCD-grouped bijective swizzle (1024 blocks, 8 XCDs, nwg%8==0):
  const int bid = blockIdx.x;
  const int xcd = bid & 7;
  const int jj = bid >> 3;              // 0..127 within XCD
  const int cs = xcd * 4 + (jj >> 5);   // key-slice 0..31 (4 per XCD)
  const int rb = jj & 31;               // q-row-block 0..31
  const int m0 = rb * 128;
  const int lane = t & 63, wv = t >> 6;
  const int wr = wv >> 1, wc = wv & 1;
  const int q4 = lane >> 4, lx = lane & 15;

  if (t < 128) lcnt[t] = 0;  // ordered before first scan by chunk-loop barriers

  // DMA lane geometry: one gload_lds instr = 64 lanes x 16 B = 8 rows x 128 B.
  // Linear dest (HW: base + lane*16); source byte pre-swizzled so that
  // LDS[row][w] = G[row][w ^ ((row&7)<<4)].
  const int lr8 = lane >> 3;                         // sub-row 0..7
  const int lsw = ((lane & 7) * 16) ^ (lr8 << 4);    // swizzled byte in 128B
  const char* qbase = (const char*)qh;
  const char* kbase = (const char*)kh;
  char* AsB = (char*)AsL;
  char* BsB = (char*)BsL;

  for (int tile = 0; tile < 8; ++tile) {
    const int n0 = cs * 1024 + tile * 128;
    const floatx4 vzero = {0.f, 0.f, 0.f, 0.f};
    floatx4 acc[4][4];
#pragma unroll
    for (int i = 0; i < 4; i++)
#pragma unroll
      for (int j = 0; j < 4; j++) acc[i][j] = vzero;

    for (int chunk = 0; chunk < 4; ++chunk) {
      __syncthreads();  // prior tile/chunk LDS reads complete
      const int cb = chunk * 128;  // byte offset within 512 B source row
#pragma unroll
      for (int u = 0; u < 4; u++) {
        const int s = wv * 4 + u;            // staging instr 0..15
        const int row = s * 8 + lr8;         // tile-relative row 0..127
        GLD16(qbase + ((long)(m0 + row) << 9) + cb + lsw, AsB + s * 1024);
        GLD16(kbase + ((long)(n0 + row) << 9) + cb + lsw, BsB + s * 1024);
      }
      __syncthreads();  // vmcnt drain -> staged data visible
#pragma unroll
      for (int ks = 0; ks < 2; ++ks) {
        bf16x8 af[4], bfr[4];
        const int cbyte = (ks * 64 + q4 * 16) ^ ((lx & 7) << 4);
#pragma unroll
        for (int i = 0; i < 4; i++)
          af[i] = *(const bf16x8*)(AsB + (wr * 64 + i * 16 + lx) * 128 + cbyte);
#pragma unroll
        for (int j = 0; j < 4; j++)
          bfr[j] = *(const bf16x8*)(BsB + (wc * 64 + j * 16 + lx) * 128 + cbyte);
#pragma unroll
        for (int i = 0; i < 4; i++)
#pragma unroll
          for (int j = 0; j < 4; j++)
            acc[i][j] = __builtin_amdgcn_mfma_f32_16x16x32_bf16(af[i], bfr[j], acc[i][j], 0, 0, 0);
      }
    }

    // threshold scan -> per-row LDS lists. Wave-uniform __any pre-skip per
    // 16-value group (~73% skipped), then ballot-batched LDS atomics (one
    // atomic per active 16-lane group).
#pragma unroll
    for (int i = 0; i < 4; i++)
#pragma unroll
      for (int j = 0; j < 4; j++) {
        const float m01 = fmaxf(acc[i][j][0], acc[i][j][1]);
        const float m23 = fmaxf(acc[i][j][2], acc[i][j][3]);
        if (__any(fmaxf(m01, m23) > TAU)) {
#pragma unroll
          for (int r = 0; r < 4; r++) {
            const float v = acc[i][j][r];
            const unsigned long long mask = __ballot(v > TAU);
            if (v > TAU) {
              const int rloc = wr * 64 + i * 16 + q4 * 4 + r;  // 0..127
              const int idx = n0 + wc * 64 + j * 16 + lx;
              const unsigned int gm = (unsigned int)((mask >> (q4 * 16)) & 0xFFFFull);
              const int rank = __popc(gm & ((1u << lx) - 1u));
              const int leader = __ffs(gm) - 1;                // sub-lane in group
              int base = 0;
              if (lx == leader) base = atomicAdd(&lcnt[rloc], __popc(gm));
              base = __shfl(base, q4 * 16 + leader, 64);
              const int slot = base + rank;
              const unsigned int pk = (__float_as_uint(v) & 0xFFFF8000u) | (unsigned int)idx;
              if (slot < LCAP) {
                lds_list[rloc][slot] = pk;
              } else {  // rare overflow: direct global append (correct)
                const int gs = atomicAdd(&cnt[m0 + rloc], 1);
                if (gs < CAP) cand[(long)(m0 + rloc) * CAP + gs] = pk;
              }
            }
          }
        }
      }
  }

  // flush: one global atomic per (row, block), outside the MFMA pipeline
  __syncthreads();
  if (t < 128) {
    const int n = lcnt[t];
    if (n > 0) {
      const int nk = n < LCAP ? n : LCAP;
      const int base = atomicAdd(&cnt[m0 + t], nk);
      for (int s = 0; s < nk; s++) {
        const int gs = base + s;
        if (gs < CAP) cand[(long)(m0 + t) * CAP + gs] = lds_list[t][s];
      }
    }
  }
}

// ---------------------------------------------------------------------------
// Refine: one wave per row. Coarse top-48 of the candidate list (monotone u32
// keys), exact fp32 rescore vs original keys, exact top-32 (jax tie-break:
// value desc then idx asc), softmax.
// ---------------------------------------------------------------------------
__global__ __launch_bounds__(256) void refine_kernel(const float* __restrict__ q,
                                                     const float* __restrict__ qinv,
                                                     const float* __restrict__ keys,
                                                     const float* __restrict__ kinv,
                                                     const int* __restrict__ cnt,
                                                     const unsigned int* __restrict__ cand,
                                                     float* __restrict__ w_top,
                                                     int* __restrict__ i_top) {
  const int row = blockIdx.x * 4 + (threadIdx.x >> 6);
  const int lane = threadIdx.x & 63;
  // q-hat fragment (4 k-dims per lane), same elementwise values as numpy's q_norm
  const float qs = qinv[row];
  float4 qh = ((const float4*)(q + (long)row * 256))[lane];
  qh.x *= qs; qh.y *= qs; qh.z *= qs; qh.w *= qs;
  int ncand = cnt[row];
  if (ncand > CAP) ncand = CAP;
  unsigned int loc[8];
#pragma unroll
  for (int s = 0; s < 8; s++) {
    const int c = s * 64 + lane;
    loc[s] = (c < ncand) ? cand[(long)row * CAP + c] : 0u;
  }
  // coarse top-48 by u32 key (monotone in bf16 sim; ties resolved by rescore)
  unsigned int mykey = 0;
  for (int it = 0; it < 48; ++it) {
    unsigned int best = loc[0];
#pragma unroll
    for (int s = 1; s < 8; s++) best = (loc[s] > best) ? loc[s] : best;
#pragma unroll
    for (int o = 32; o > 0; o >>= 1) {
      const unsigned int oth = __shfl_xor(best, o, 64);
      if (oth > best) best = oth;
    }
    if (best == 0u) break;  // wave-uniform: list exhausted
#pragma unroll
    for (int s = 0; s < 8; s++)
      if (loc[s] == best) loc[s] = 0;  // keys unique per row
    if (lane == it) mykey = best;
  }
  const int myidx = (int)(mykey & 0x7FFFu);
  // exact fp32 rescore of the (up to) 48
  float myexact = 0.0f;
  for (int c = 0; c < 48; ++c) {
    const unsigned int ky = __shfl(mykey, c, 64);
    if (ky == 0u) continue;  // wave-uniform branch
    const int idx = (int)(ky & 0x7FFFu);
    const float4 kv = ((const float4*)(keys + (long)idx * 256))[lane];
    float d = qh.x * kv.x + qh.y * kv.y + qh.z * kv.z + qh.w * kv.w;
    d = wave_sum(d);
    const float sim = d * kinv[idx];
    if (lane == c) myexact = sim;
  }
  // exact top-32 with jax tie-break (value desc, idx asc)
  unsigned long long ekey = (lane < 48 && mykey != 0u) ? pack_vi(myexact, myidx) : 0ULL;
  unsigned long long sel = 0;
  float maxv = 0.0f;
  for (int it = 0; it < 32; ++it) {
    unsigned long long best = ekey;
#pragma unroll
    for (int o = 32; o > 0; o >>= 1) {
      const unsigned long long oth = __shfl_xor(best, o, 64);
      if (oth > best) best = oth;
    }
    if (ekey == best) ekey = 0;
    if (lane == it) sel = best;
    if (it == 0) maxv = unpack_v(best);
  }
  float e = 0.0f;
  int oidx = 0;
  if (lane < 32) {
    e = expf(unpack_v(sel) - maxv);
    oidx = unpack_i(sel);
  }
  const float ssum = wave_sum(e);
  if (lane < 32) {
    w_top[(long)row * 32 + lane] = e / ssum;
    i_top[(long)row * 32 + lane] = oidx;
  }
}

// mem_out = sum_k w_k * values[idx_k]; h = bf16(mem_out * gate). One block/row.
__global__ __launch_bounds__(256) void gather_gate_kernel(const float* __restrict__ values,
                                                          const float* __restrict__ w_top,
                                                          const int* __restrict__ i_top,
                                                          const float* __restrict__ gate,
                                                          ushort_t* __restrict__ h) {
  __shared__ float w[32];
  __shared__ int ix[32];
  const int row = blockIdx.x;
  const int t = threadIdx.x;
  if (t < 32) {
    w[t] = w_top[(long)row * 32 + t];
    ix[t] = i_top[(long)row * 32 + t];
  }
  __syncthreads();
  float4 acc = make_float4(0.f, 0.f, 0.f, 0.f);
#pragma unroll 4
  for (int k = 0; k < 32; k++) {
    const float4 v = *(const float4*)(values + (long)ix[k] * 1024 + t * 4);
    const float wk = w[k];
    acc.x = fmaf(wk, v.x, acc.x);
    acc.y = fmaf(wk, v.y, acc.y);
    acc.z = fmaf(wk, v.z, acc.z);
    acc.w = fmaf(wk, v.w, acc.w);
  }
  const float4 g = *(const float4*)(gate + (long)row * 1024 + t * 4);
  ushort4 o;
  o.x = f2bf_rne(acc.x * g.x); o.y = f2bf_rne(acc.y * g.y);
  o.z = f2bf_rne(acc.z * g.z); o.w = f2bf_rne(acc.w * g.w);
  ((ushort4*)(h + (long)row * 1024))[t] = o;
}

extern "C" void kernel_launch(void* const* d_in, const int* in_sizes, int n_in,
                              void* d_out, int out_size, void* d_ws, size_t ws_size,
                              hipStream_t stream) {
  const float* x      = (const float*)d_in[0];  // [4,1024,1024]
  const float* keys   = (const float*)d_in[1];  // [32768,256]
  const float* values = (const float*)d_in[2];  // [32768,1024]
  const float* w_q    = (const float*)d_in[3];  // [256,1024]
  const float* w_gate = (const float*)d_in[4];  // [1024,1024]
  const float* w_out  = (const float*)d_in[5];  // [1024,1024]
  float* out = (float*)d_out;                   // [4,1024,1024]

  // workspace layout (4-byte units), ~51.5 MB total
  float* q        = (float*)d_ws;                   // 1,048,576
  float* qinv     = q + 1048576;                    // 4096
  float* kinv     = qinv + 4096;                    // 32768
  int*   cnt      = (int*)(kinv + 32768);           // 4096
  float* w_top    = (float*)(cnt + 4096);           // 131072
  int*   i_top    = (int*)(w_top + 131072);         // 131072
  ushort_t* qh    = (ushort_t*)(i_top + 131072);    // 524,288 f
  float* khf      = (float*)(qh + 1048576);         // 4,194,304 f region
  ushort_t* kh    = (ushort_t*)khf;                 //   [cast -> sims]
  ushort_t* hbf   = (ushort_t*)khf;                 //   alias: h bf16 [gather -> out GEMM]
  ushort_t* wo    = (ushort_t*)(khf + 2097152);     //   alias: w_out bf16 [after sims]
  float* gate     = khf + 4194304;                  // 4,194,304 f
  float* xbfr     = gate + 4194304;                 // 2,097,152 f region
  ushort_t* xb    = (ushort_t*)xbfr;                //   x bf16 [cast -> gate GEMM]
  unsigned int* cand = (unsigned int*)xbfr;         //   alias: candidates [sims -> refine]
  ushort_t* wg    = (ushort_t*)(xbfr + 2097152);    // 524,288 f

  cast_bf16_zero_kernel<<<dim3(4096), 256, 0, stream>>>(x, xb, cnt);
  qgemm_kernel<<<dim3(4, 128), 256, 0, stream>>>(x, w_q, q);
  rownorm_cast_kernel<<<dim3(32768 / 4), 256, 0, stream>>>(keys, kinv, kh);
  rownorm_cast_kernel<<<dim3(4096 / 4), 256, 0, stream>>>(q, qinv, qh);
  cast_bf16_kernel<<<dim3(1024), 256, 0, stream>>>(w_gate, wg);
  // gate GEMM must precede sims (cand aliases xb)
  hgemm_bt_kernel<1><<<dim3(8, 32), 256, 0, stream>>>(xb, wg, gate, 4096, 1024, 1024);
  sims_coarse_kernel<<<dim3(1024), 256, 0, stream>>>(qh, kh, cnt, cand);
  // w_out cast must follow sims (wo aliases kh region)
  cast_bf16_kernel<<<dim3(1024), 256, 0, stream>>>(w_out, wo);
  refine_kernel<<<dim3(4096 / 4), 256, 0, stream>>>(q, qinv, keys, kinv, cnt, cand, w_top, i_top);
  gather_gate_kernel<<<dim3(4096), 256, 0, stream>>>(values, w_top, i_top, gate, hbf);
  hgemm_bt_kernel<0><<<dim3(8, 32), 256, 0, stream>>>(hbf, wo, out, 4096, 1024, 1024);
}

// Round 8
// 608.569 us; speedup vs baseline: 1.6455x; 1.1318x over previous
//
#include <hip/hip_runtime.h>
#include <cmath>
#include <cstdint>

// ---------------------------------------------------------------------------
// MemoryPlus: q = x@w_q^T; sims = norm(q)@norm(keys)^T; top-32 + softmax;
// mem_out = sum_k w_k * values[idx_k]; out = (mem_out * silu(x@w_gate^T)) @ w_out^T
//
// R12:
//  (a) sims: R10's (256,4) re-introduced a small spill (VGPR 104+AGPR 64=168
//      > 128 cap; WRITE 6.7->79 MB) AND L2 thrash (4 blocks/CU -> per-XCD
//      working set 4MB == L2 size; FETCH 16.5->215 MB). Revert to 3/CU via
//      (256,3): budget 170 >= 168, working set 3.5MB < 4MB.
//  (b) hgemm_bt (gate+out): port sims' verified GLD16 DMA staging + both-
//      sides XOR swizzle (m151: gload_lds ~35% faster than reg-staging at
//      this tile). LDS 36.9->32KB, no prefetch regs, (256,3) -> 3 blocks/CU.
// ---------------------------------------------------------------------------

typedef unsigned short ushort_t;
typedef __bf16 bf16x8 __attribute__((ext_vector_type(8)));
typedef float floatx4 __attribute__((ext_vector_type(4)));

#define TAU 0.16f
#define CAP 512
#define LCAP 15

#define GLD16(g, l)                                                      \
  __builtin_amdgcn_global_load_lds(                                      \
      (const __attribute__((address_space(1))) unsigned int*)(g),        \
      (__attribute__((address_space(3))) unsigned int*)(l), 16, 0, 0)

__device__ __forceinline__ float wave_sum(float v) {
#pragma unroll
  for (int o = 32; o > 0; o >>= 1) v += __shfl_xor(v, o, 64);
  return v;
}

__device__ __forceinline__ unsigned long long pack_vi(float v, int idx) {
  const unsigned int b = __float_as_uint(v);
  const unsigned int fk = (b & 0x80000000u) ? ~b : (b | 0x80000000u);
  return ((unsigned long long)fk << 32) | (unsigned int)(~idx);
}
__device__ __forceinline__ float unpack_v(unsigned long long k) {
  const unsigned int fk = (unsigned int)(k >> 32);
  const unsigned int b = (fk & 0x80000000u) ? (fk & 0x7FFFFFFFu) : ~fk;
  return __uint_as_float(b);
}
__device__ __forceinline__ int unpack_i(unsigned long long k) {
  return ~(int)(unsigned int)(k & 0xFFFFFFFFu);
}

__device__ __forceinline__ ushort_t f2bf_rne(float f) {
  const unsigned int u = __float_as_uint(f);
  return (ushort_t)((u + 0x7FFFu + ((u >> 16) & 1u)) >> 16);
}

// fused: inverse L2 norm of each 256-float row + normalized bf16 cast.
__global__ __launch_bounds__(256) void rownorm_cast_kernel(const float* __restrict__ rows,
                                                           float* __restrict__ inv,
                                                           ushort_t* __restrict__ out) {
  const int r = blockIdx.x * 4 + (threadIdx.x >> 6);
  const int lane = threadIdx.x & 63;
  const float4 v = ((const float4*)(rows + (long)r * 256))[lane];
  float s = v.x * v.x + v.y * v.y + v.z * v.z + v.w * v.w;
  s = wave_sum(s);
  const float sc = 1.0f / fmaxf(sqrtf(s), 1e-12f);
  if (lane == 0) inv[r] = sc;
  ushort4 o;
  o.x = f2bf_rne(v.x * sc); o.y = f2bf_rne(v.y * sc);
  o.z = f2bf_rne(v.z * sc); o.w = f2bf_rne(v.w * sc);
  ((ushort4*)(out + (long)r * 256))[lane] = o;
}

// plain fp32 -> bf16 cast, one float4 per thread
__global__ __launch_bounds__(256) void cast_bf16_kernel(const float* __restrict__ in,
                                                        ushort_t* __restrict__ out) {
  const long idx = (long)blockIdx.x * 256 + threadIdx.x;
  const float4 v = ((const float4*)in)[idx];
  ushort4 o;
  o.x = f2bf_rne(v.x); o.y = f2bf_rne(v.y);
  o.z = f2bf_rne(v.z); o.w = f2bf_rne(v.w);
  ((ushort4*)out)[idx] = o;
}

// x cast + fused cnt zeroing (cnt untouched until sims, which runs later)
__global__ __launch_bounds__(256) void cast_bf16_zero_kernel(const float* __restrict__ in,
                                                             ushort_t* __restrict__ out,
                                                             int* __restrict__ cnt) {
  if (blockIdx.x < 16) cnt[blockIdx.x * 256 + threadIdx.x] = 0;
  const long idx = (long)blockIdx.x * 256 + threadIdx.x;
  const float4 v = ((const float4*)in)[idx];
  ushort4 o;
  o.x = f2bf_rne(v.x); o.y = f2bf_rne(v.y);
  o.z = f2bf_rne(v.z); o.w = f2bf_rne(v.w);
  ((ushort4*)out)[idx] = o;
}

// fp32 q GEMM: C[4096,256] = A[4096,1024] @ B[256,1024]^T. 32x64 tile,
// 2x4/thread, BK=32, grid (4,128)=512 blocks. Same K-order -> bit-identical q.
__global__ __launch_bounds__(256) void qgemm_kernel(const float* __restrict__ A,
                                                    const float* __restrict__ B,
                                                    float* __restrict__ C) {
  __shared__ float As[32][32];
  __shared__ float Bs[32][64];
  const int t = threadIdx.x;
  const int tx = t & 15, ty = t >> 4;
  const int m0 = blockIdx.y * 32, n0 = blockIdx.x * 64;
  const int lrA = t >> 3;          // A row 0..31 (8 threads/row)
  const int lkA = (t & 7) * 4;     // k offset 0,4,..,28
  const int lrB = t >> 2;          // B row 0..63 (4 threads/row)
  const int lkB = (t & 3) * 8;     // k offset 0,8,16,24
  const float* Ap = A + (long)(m0 + lrA) * 1024 + lkA;
  const float* Bp = B + (long)(n0 + lrB) * 1024 + lkB;
  float acc[2][4] = {};
  for (int kc = 0; kc < 1024; kc += 32) {
    const float4 a0 = *(const float4*)(Ap + kc);
    const float4 b0 = *(const float4*)(Bp + kc);
    const float4 b1 = *(const float4*)(Bp + kc + 4);
    __syncthreads();
    As[lkA + 0][lrA] = a0.x; As[lkA + 1][lrA] = a0.y;
    As[lkA + 2][lrA] = a0.z; As[lkA + 3][lrA] = a0.w;
    Bs[lkB + 0][lrB] = b0.x; Bs[lkB + 1][lrB] = b0.y; Bs[lkB + 2][lrB] = b0.z; Bs[lkB + 3][lrB] = b0.w;
    Bs[lkB + 4][lrB] = b1.x; Bs[lkB + 5][lrB] = b1.y; Bs[lkB + 6][lrB] = b1.z; Bs[lkB + 7][lrB] = b1.w;
    __syncthreads();
#pragma unroll
    for (int kk = 0; kk < 32; kk++) {
      const float2 a = *(const float2*)&As[kk][ty * 2];
      const float4 b = *(const float4*)&Bs[kk][tx * 4];
      const float av[2] = {a.x, a.y};
      const float bv[4] = {b.x, b.y, b.z, b.w};
#pragma unroll
      for (int i = 0; i < 2; i++)
#pragma unroll
        for (int j = 0; j < 4; j++) acc[i][j] = fmaf(av[i], bv[j], acc[i][j]);
    }
  }
#pragma unroll
  for (int i = 0; i < 2; i++) {
    float* Cr = C + (long)(m0 + ty * 2 + i) * 256 + n0 + tx * 4;
    *(float4*)Cr = make_float4(acc[i][0], acc[i][1], acc[i][2], acc[i][3]);
  }
}

// bf16 MFMA GEMM: C[M,N] fp32 = A[M,K]bf16 @ B[N,K]bf16^T. 128x128 tile,
// 4 waves each 64x64 (4x4 of 16x16x32), BK=64. GLD16 DMA staging into linear
// [128][64] tiles with both-sides XOR swizzle (same verified pattern as sims).
template <int EP>  // 0 = none, 1 = silu
__global__ __launch_bounds__(256, 3) void hgemm_bt_kernel(const ushort_t* __restrict__ A,
                                                          const ushort_t* __restrict__ B,
                                                          float* __restrict__ C,
                                                          int M, int N, int K) {
  __shared__ __align__(16) ushort_t AsL[128 * 64];
  __shared__ __align__(16) ushort_t BsL[128 * 64];
  const int t = threadIdx.x;
  const int m0 = blockIdx.y * 128, n0 = blockIdx.x * 128;
  const int lane = t & 63, wv = t >> 6;
  const int wr = wv >> 1, wc = wv & 1;
  const int q4 = lane >> 4, lx = lane & 15;
  const int lr8 = lane >> 3;                         // sub-row 0..7
  const int lsw = ((lane & 7) * 16) ^ (lr8 << 4);    // swizzled byte in 128B
  const char* Ab = (const char*)A;
  const char* Bb = (const char*)B;
  char* AsB = (char*)AsL;
  char* BsB = (char*)BsL;
  const long rs = (long)K * 2;  // row stride bytes
  const floatx4 vzero = {0.f, 0.f, 0.f, 0.f};
  floatx4 acc[4][4];
#pragma unroll
  for (int i = 0; i < 4; i++)
#pragma unroll
    for (int j = 0; j < 4; j++) acc[i][j] = vzero;

  const int NC = K >> 6;
  for (int c = 0; c < NC; ++c) {
    __syncthreads();  // prior chunk LDS reads complete
    const long cb = (long)c * 128;  // byte offset within source row
#pragma unroll
    for (int u = 0; u < 4; u++) {
      const int s = wv * 4 + u;            // staging instr 0..15
      const int row = s * 8 + lr8;         // tile-relative row 0..127
      GLD16(Ab + (long)(m0 + row) * rs + cb + lsw, AsB + s * 1024);
      GLD16(Bb + (long)(n0 + row) * rs + cb + lsw, BsB + s * 1024);
    }
    __syncthreads();  // vmcnt drain -> staged data visible
#pragma unroll
    for (int ks = 0; ks < 2; ++ks) {
      bf16x8 af[4], bfr[4];
      const int cbyte = (ks * 64 + q4 * 16) ^ ((lx & 7) << 4);
#pragma unroll
      for (int i = 0; i < 4; i++)
        af[i] = *(const bf16x8*)(AsB + (wr * 64 + i * 16 + lx) * 128 + cbyte);
#pragma unroll
      for (int j = 0; j < 4; j++)
        bfr[j] = *(const bf16x8*)(BsB + (wc * 64 + j * 16 + lx) * 128 + cbyte);
#pragma unroll
      for (int i = 0; i < 4; i++)
#pragma unroll
        for (int j = 0; j < 4; j++)
          acc[i][j] = __builtin_amdgcn_mfma_f32_16x16x32_bf16(af[i], bfr[j], acc[i][j], 0, 0, 0);
    }
  }
#pragma unroll
  for (int i = 0; i < 4; i++)
#pragma unroll
    for (int j = 0; j < 4; j++) {
      const int col = n0 + wc * 64 + j * 16 + lx;
#pragma unroll
      for (int r = 0; r < 4; r++) {
        const int row = m0 + wr * 64 + i * 16 + q4 * 4 + r;
        float v = acc[i][j][r];
        if (EP == 1) v = v / (1.0f + expf(-v));  // silu
        C[(long)row * N + col] = v;
      }
    }
}

// ---------------------------------------------------------------------------
// Coarse sims: bf16 MFMA GEMM, block = 128 q-rows x 1024 keys (8 tiles of
// 128), K=256 in 4 chunks of 64. GLD16 DMA staging, both-sides XOR swizzle.
// Scan: per-row LDS lists (LCAP=15; overflow -> direct global append),
// ballot-batched LDS atomics with __any pre-skip; one global atomic per
// (row,block) flush. (256,3): 3 blocks/CU -> per-XCD working set 3.5MB < L2,
// reg budget 170 >= 168 (104 VGPR + 64 AGPR) -> no spill.
// ---------------------------------------------------------------------------
__global__ __launch_bounds__(256, 3) void sims_coarse_kernel(const ushort_t* __restrict__ qh,
                                                             const ushort_t* __restrict__ kh,
                                                             int* __restrict__ cnt,
                                                             unsigned int* __restrict__ cand) {
  __shared__ __align__(16) ushort_t AsL[128 * 64];
  __shared__ __align__(16) ushort_t BsL[128 * 64];
  __shared__ unsigned int lds_list[128][LCAP];
  __shared__ int lcnt[128];
  const int t = threadIdx.x;
  // XCD-grouped bijective swizzle (1024 blocks, 8 XCDs, nwg%8==0):
  const int bid = blockIdx.x;
  const int xcd = bid & 7;
  const int jj = bid >> 3;              // 0..127 within XCD
  const int cs = xcd * 4 + (jj >> 5);   // key-slice 0..31 (4 per XCD)
  const int rb = jj & 31;               // q-row-block 0..31
  const int m0 = rb * 128;
  const int lane = t & 63, wv = t >> 6;
  const int wr = wv >> 1, wc = wv & 1;
  const int q4 = lane >> 4, lx = lane & 15;

  if (t < 128) lcnt[t] = 0;  // ordered before first scan by chunk-loop barriers

  // DMA lane geometry: one gload_lds instr = 64 lanes x 16 B = 8 rows x 128 B.
  const int lr8 = lane >> 3;                         // sub-row 0..7
  const int lsw = ((lane & 7) * 16) ^ (lr8 << 4);    // swizzled byte in 128B
  const char* qbase = (const char*)qh;
  const char* kbase = (const char*)kh;
  char* AsB = (char*)AsL;
  char* BsB = (char*)BsL;

  for (int tile = 0; tile < 8; ++tile) {
    const int n0 = cs * 1024 + tile * 128;
    const floatx4 vzero = {0.f, 0.f, 0.f, 0.f};
    floatx4 acc[4][4];
#pragma unroll
    for (int i = 0; i < 4; i++)
#pragma unroll
      for (int j = 0; j < 4; j++) acc[i][j] = vzero;

    for (int chunk = 0; chunk < 4; ++chunk) {
      __syncthreads();  // prior tile/chunk LDS reads complete
      const int cb = chunk * 128;  // byte offset within 512 B source row
#pragma unroll
      for (int u = 0; u < 4; u++) {
        const int s = wv * 4 + u;            // staging instr 0..15
        const int row = s * 8 + lr8;         // tile-relative row 0..127
        GLD16(qbase + ((long)(m0 + row) << 9) + cb + lsw, AsB + s * 1024);
        GLD16(kbase + ((long)(n0 + row) << 9) + cb + lsw, BsB + s * 1024);
      }
      __syncthreads();  // vmcnt drain -> staged data visible
#pragma unroll
      for (int ks = 0; ks < 2; ++ks) {
        bf16x8 af[4], bfr[4];
        const int cbyte = (ks * 64 + q4 * 16) ^ ((lx & 7) << 4);
#pragma unroll
        for (int i = 0; i < 4; i++)
          af[i] = *(const bf16x8*)(AsB + (wr * 64 + i * 16 + lx) * 128 + cbyte);
#pragma unroll
        for (int j = 0; j < 4; j++)
          bfr[j] = *(const bf16x8*)(BsB + (wc * 64 + j * 16 + lx) * 128 + cbyte);
#pragma unroll
        for (int i = 0; i < 4; i++)
#pragma unroll
          for (int j = 0; j < 4; j++)
            acc[i][j] = __builtin_amdgcn_mfma_f32_16x16x32_bf16(af[i], bfr[j], acc[i][j], 0, 0, 0);
      }
    }

    // threshold scan -> per-row LDS lists. Wave-uniform __any pre-skip per
    // 16-value group (~73% skipped), then ballot-batched LDS atomics.
#pragma unroll
    for (int i = 0; i < 4; i++)
#pragma unroll
      for (int j = 0; j < 4; j++) {
        const float m01 = fmaxf(acc[i][j][0], acc[i][j][1]);
        const float m23 = fmaxf(acc[i][j][2], acc[i][j][3]);
        if (__any(fmaxf(m01, m23) > TAU)) {
#pragma unroll
          for (int r = 0; r < 4; r++) {
            const float v = acc[i][j][r];
            const unsigned long long mask = __ballot(v > TAU);
            if (v > TAU) {
              const int rloc = wr * 64 + i * 16 + q4 * 4 + r;  // 0..127
              const int idx = n0 + wc * 64 + j * 16 + lx;
              const unsigned int gm = (unsigned int)((mask >> (q4 * 16)) & 0xFFFFull);
              const int rank = __popc(gm & ((1u << lx) - 1u));
              const int leader = __ffs(gm) - 1;                // sub-lane in group
              int base = 0;
              if (lx == leader) base = atomicAdd(&lcnt[rloc], __popc(gm));
              base = __shfl(base, q4 * 16 + leader, 64);
              const int slot = base + rank;
              const unsigned int pk = (__float_as_uint(v) & 0xFFFF8000u) | (unsigned int)idx;
              if (slot < LCAP) {
                lds_list[rloc][slot] = pk;
              } else {  // rare overflow: direct global append (correct)
                const int gs = atomicAdd(&cnt[m0 + rloc], 1);
                if (gs < CAP) cand[(long)(m0 + rloc) * CAP + gs] = pk;
              }
            }
          }
        }
      }
  }

  // flush: one global atomic per (row, block), outside the MFMA pipeline
  __syncthreads();
  if (t < 128) {
    const int n = lcnt[t];
    if (n > 0) {
      const int nk = n < LCAP ? n : LCAP;
      const int base = atomicAdd(&cnt[m0 + t], nk);
      for (int s = 0; s < nk; s++) {
        const int gs = base + s;
        if (gs < CAP) cand[(long)(m0 + t) * CAP + gs] = lds_list[t][s];
      }
    }
  }
}

// ---------------------------------------------------------------------------
// Refine: one wave per row. Coarse top-48 of the candidate list (monotone u32
// keys), exact fp32 rescore vs original keys, exact top-32 (jax tie-break:
// value desc then idx asc), softmax.
// ---------------------------------------------------------------------------
__global__ __launch_bounds__(256) void refine_kernel(const float* __restrict__ q,
                                                     const float* __restrict__ qinv,
                                                     const float* __restrict__ keys,
                                                     const float* __restrict__ kinv,
                                                     const int* __restrict__ cnt,
                                                     const unsigned int* __restrict__ cand,
                                                     float* __restrict__ w_top,
                                                     int* __restrict__ i_top) {
  const int row = blockIdx.x * 4 + (threadIdx.x >> 6);
  const int lane = threadIdx.x & 63;
  const float qs = qinv[row];
  float4 qh = ((const float4*)(q + (long)row * 256))[lane];
  qh.x *= qs; qh.y *= qs; qh.z *= qs; qh.w *= qs;
  int ncand = cnt[row];
  if (ncand > CAP) ncand = CAP;
  unsigned int loc[8];
#pragma unroll
  for (int s = 0; s < 8; s++) {
    const int c = s * 64 + lane;
    loc[s] = (c < ncand) ? cand[(long)row * CAP + c] : 0u;
  }
  // coarse top-48 by u32 key (monotone in bf16 sim; ties resolved by rescore)
  unsigned int mykey = 0;
  for (int it = 0; it < 48; ++it) {
    unsigned int best = loc[0];
#pragma unroll
    for (int s = 1; s < 8; s++) best = (loc[s] > best) ? loc[s] : best;
#pragma unroll
    for (int o = 32; o > 0; o >>= 1) {
      const unsigned int oth = __shfl_xor(best, o, 64);
      if (oth > best) best = oth;
    }
    if (best == 0u) break;  // wave-uniform: list exhausted
#pragma unroll
    for (int s = 0; s < 8; s++)
      if (loc[s] == best) loc[s] = 0;  // keys unique per row
    if (lane == it) mykey = best;
  }
  const int myidx = (int)(mykey & 0x7FFFu);
  // exact fp32 rescore of the (up to) 48
  float myexact = 0.0f;
  for (int c = 0; c < 48; ++c) {
    const unsigned int ky = __shfl(mykey, c, 64);
    if (ky == 0u) continue;  // wave-uniform branch
    const int idx = (int)(ky & 0x7FFFu);
    const float4 kv = ((const float4*)(keys + (long)idx * 256))[lane];
    float d = qh.x * kv.x + qh.y * kv.y + qh.z * kv.z + qh.w * kv.w;
    d = wave_sum(d);
    const float sim = d * kinv[idx];
    if (lane == c) myexact = sim;
  }
  // exact top-32 with jax tie-break (value desc, idx asc)
  unsigned long long ekey = (lane < 48 && mykey != 0u) ? pack_vi(myexact, myidx) : 0ULL;
  unsigned long long sel = 0;
  float maxv = 0.0f;
  for (int it = 0; it < 32; ++it) {
    unsigned long long best = ekey;
#pragma unroll
    for (int o = 32; o > 0; o >>= 1) {
      const unsigned long long oth = __shfl_xor(best, o, 64);
      if (oth > best) best = oth;
    }
    if (ekey == best) ekey = 0;
    if (lane == it) sel = best;
    if (it == 0) maxv = unpack_v(best);
  }
  float e = 0.0f;
  int oidx = 0;
  if (lane < 32) {
    e = expf(unpack_v(sel) - maxv);
    oidx = unpack_i(sel);
  }
  const float ssum = wave_sum(e);
  if (lane < 32) {
    w_top[(long)row * 32 + lane] = e / ssum;
    i_top[(long)row * 32 + lane] = oidx;
  }
}

// mem_out = sum_k w_k * values[idx_k]; h = bf16(mem_out * gate). One block/row.
__global__ __launch_bounds__(256) void gather_gate_kernel(const float* __restrict__ values,
                                                          const float* __restrict__ w_top,
                                                          const int* __restrict__ i_top,
                                                          const float* __restrict__ gate,
                                                          ushort_t* __restrict__ h) {
  __shared__ float w[32];
  __shared__ int ix[32];
  const int row = blockIdx.x;
  const int t = threadIdx.x;
  if (t < 32) {
    w[t] = w_top[(long)row * 32 + t];
    ix[t] = i_top[(long)row * 32 + t];
  }
  __syncthreads();
  float4 acc = make_float4(0.f, 0.f, 0.f, 0.f);
#pragma unroll 4
  for (int k = 0; k < 32; k++) {
    const float4 v = *(const float4*)(values + (long)ix[k] * 1024 + t * 4);
    const float wk = w[k];
    acc.x = fmaf(wk, v.x, acc.x);
    acc.y = fmaf(wk, v.y, acc.y);
    acc.z = fmaf(wk, v.z, acc.z);
    acc.w = fmaf(wk, v.w, acc.w);
  }
  const float4 g = *(const float4*)(gate + (long)row * 1024 + t * 4);
  ushort4 o;
  o.x = f2bf_rne(acc.x * g.x); o.y = f2bf_rne(acc.y * g.y);
  o.z = f2bf_rne(acc.z * g.z); o.w = f2bf_rne(acc.w * g.w);
  ((ushort4*)(h + (long)row * 1024))[t] = o;
}

extern "C" void kernel_launch(void* const* d_in, const int* in_sizes, int n_in,
                              void* d_out, int out_size, void* d_ws, size_t ws_size,
                              hipStream_t stream) {
  const float* x      = (const float*)d_in[0];  // [4,1024,1024]
  const float* keys   = (const float*)d_in[1];  // [32768,256]
  const float* values = (const float*)d_in[2];  // [32768,1024]
  const float* w_q    = (const float*)d_in[3];  // [256,1024]
  const float* w_gate = (const float*)d_in[4];  // [1024,1024]
  const float* w_out  = (const float*)d_in[5];  // [1024,1024]
  float* out = (float*)d_out;                   // [4,1024,1024]

  // workspace layout (4-byte units), ~51.5 MB total
  float* q        = (float*)d_ws;                   // 1,048,576
  float* qinv     = q + 1048576;                    // 4096
  float* kinv     = qinv + 4096;                    // 32768
  int*   cnt      = (int*)(kinv + 32768);           // 4096
  float* w_top    = (float*)(cnt + 4096);           // 131072
  int*   i_top    = (int*)(w_top + 131072);         // 131072
  ushort_t* qh    = (ushort_t*)(i_top + 131072);    // 524,288 f
  float* khf      = (float*)(qh + 1048576);         // 4,194,304 f region
  ushort_t* kh    = (ushort_t*)khf;                 //   [cast -> sims]
  ushort_t* hbf   = (ushort_t*)khf;                 //   alias: h bf16 [gather -> out GEMM]
  ushort_t* wo    = (ushort_t*)(khf + 2097152);     //   alias: w_out bf16 [after sims]
  float* gate     = khf + 4194304;                  // 4,194,304 f
  float* xbfr     = gate + 4194304;                 // 2,097,152 f region
  ushort_t* xb    = (ushort_t*)xbfr;                //   x bf16 [cast -> gate GEMM]
  unsigned int* cand = (unsigned int*)xbfr;         //   alias: candidates [sims -> refine]
  ushort_t* wg    = (ushort_t*)(xbfr + 2097152);    // 524,288 f

  cast_bf16_zero_kernel<<<dim3(4096), 256, 0, stream>>>(x, xb, cnt);
  qgemm_kernel<<<dim3(4, 128), 256, 0, stream>>>(x, w_q, q);
  rownorm_cast_kernel<<<dim3(32768 / 4), 256, 0, stream>>>(keys, kinv, kh);
  rownorm_cast_kernel<<<dim3(4096 / 4), 256, 0, stream>>>(q, qinv, qh);
  cast_bf16_kernel<<<dim3(1024), 256, 0, stream>>>(w_gate, wg);
  // gate GEMM must precede sims (cand aliases xb)
  hgemm_bt_kernel<1><<<dim3(8, 32), 256, 0, stream>>>(xb, wg, gate, 4096, 1024, 1024);
  sims_coarse_kernel<<<dim3(1024), 256, 0, stream>>>(qh, kh, cnt, cand);
  // w_out cast must follow sims (wo aliases kh region)
  cast_bf16_kernel<<<dim3(1024), 256, 0, stream>>>(w_out, wo);
  refine_kernel<<<dim3(4096 / 4), 256, 0, stream>>>(q, qinv, keys, kinv, cnt, cand, w_top, i_top);
  gather_gate_kernel<<<dim3(4096), 256, 0, stream>>>(values, w_top, i_top, gate, hbf);
  hgemm_bt_kernel<0><<<dim3(8, 32), 256, 0, stream>>>(hbf, wo, out, 4096, 1024, 1024);
}